// Round 3
// baseline (216.484 us; speedup 1.0000x reference)
//
#include <hip/hip_runtime.h>

typedef unsigned int uint;
typedef unsigned short ushort;
typedef __attribute__((ext_vector_type(8))) short short8;
typedef __attribute__((ext_vector_type(4))) float f32x4;

#define DEV static __device__ __forceinline__

DEV float bf_lo(uint v) { return __uint_as_float(v << 16); }
DEV float bf_hi(uint v) { return __uint_as_float(v & 0xffff0000u); }
DEV ushort f2bf(float f) {
    uint u = __float_as_uint(f);
    u += 0x7fffu + ((u >> 16) & 1u);   // round-to-nearest-even
    return (ushort)(u >> 16);
}
DEV void stC(float* p, float v) { *p = v; }
DEV void stC(ushort* p, float v) { *p = f2bf(v); }

// ---------------------------------------------------------------------------
__global__ void f2bf_kernel(const float* __restrict__ in, ushort* __restrict__ out, int n4)
{
    int i = blockIdx.x * 256 + threadIdx.x;
    if (i >= n4) return;
    float4 v = reinterpret_cast<const float4*>(in)[i];
    ushort4 o;
    o.x = f2bf(v.x); o.y = f2bf(v.y); o.z = f2bf(v.z); o.w = f2bf(v.w);
    reinterpret_cast<ushort4*>(out)[i] = o;
}

__global__ void transp_bf_kernel(const float* __restrict__ in, ushort* __restrict__ outT,
                                 int K, int NC)
{
    int tid = blockIdx.x * 256 + threadIdx.x;
    if (tid >= K * NC) return;
    int n = tid % NC, k = tid / NC;
    outT[(size_t)n * K + k] = f2bf(in[tid]);
}

// MPT[c, i] (bf16, [2048][128] = B^T for the GVO gemm)
__global__ void build_mpt_kernel(const float* __restrict__ Wq, const float* __restrict__ Wk,
                                 const float* __restrict__ Wv, const float* __restrict__ Wo,
                                 ushort* __restrict__ MPT)
{
    int idx = blockIdx.x * 256 + threadIdx.x;
    if (idx >= 128 * 2048) return;
    int i = idx >> 11;
    int c = idx & 2047;
    int h = (c >> 7) & 7;
    int j = c & 127;
    float s = 0.f;
    if (c < 1024) {
        const float* a = Wq + i * 1024 + h * 128;
        const float* b = Wk + j * 1024 + h * 128;
#pragma unroll 8
        for (int t = 0; t < 128; ++t) s += a[t] * b[t];
        s *= 0.08838834764831845f;  // 1/sqrt(128)
    } else {
        const float* a = Wv + i * 1024 + h * 128;
        const float* b = Wo + (h * 128) * 128 + j;
#pragma unroll 8
        for (int t = 0; t < 128; ++t) s += a[t] * b[(size_t)t * 128];
    }
    MPT[(size_t)c * 128 + i] = f2bf(s);
}

// ---------------------------------------------------------------------------
// CSR build: histogram -> block scan -> scatter
// ---------------------------------------------------------------------------
__global__ void hist_kernel(const int* __restrict__ src, const int* __restrict__ dst,
                            int* __restrict__ cnts, int* __restrict__ cntd, int E)
{
    int e = blockIdx.x * 256 + threadIdx.x;
    if (e >= E) return;
    atomicAdd(&cnts[src[e]], 1);
    atomicAdd(&cntd[dst[e]], 1);
}

__global__ __launch_bounds__(1024) void scan2_kernel(
    const int* __restrict__ cnts, const int* __restrict__ cntd,
    int* __restrict__ offs, int* __restrict__ offd,
    int* __restrict__ curs, int* __restrict__ curd, int N)
{
    __shared__ int ls[1024];
    const int t = threadIdx.x;
    const int chunk = (N + 1023) >> 10;
#pragma unroll 1
    for (int a = 0; a < 2; ++a) {
        const int* in = a ? cntd : cnts;
        int* off = a ? offd : offs;
        int* cur = a ? curd : curs;
        int base = t * chunk;
        int s = 0;
        for (int i = 0; i < chunk; ++i) {
            int idx = base + i;
            if (idx < N) s += in[idx];
        }
        ls[t] = s;
        __syncthreads();
        for (int d = 1; d < 1024; d <<= 1) {
            int v = (t >= d) ? ls[t - d] : 0;
            __syncthreads();
            ls[t] += v;
            __syncthreads();
        }
        int run = t ? ls[t - 1] : 0;
        for (int i = 0; i < chunk; ++i) {
            int idx = base + i;
            if (idx < N) {
                off[idx] = run;
                cur[idx] = run;
                run += in[idx];
            }
        }
        if (t == 1023) off[N] = run;
        __syncthreads();
    }
}

__global__ void scat_kernel(const int* __restrict__ src, const int* __restrict__ dst,
                            int* __restrict__ curs, int* __restrict__ curd,
                            int* __restrict__ perm_src, int* __restrict__ perm_dst,
                            int* __restrict__ dpos, int E)
{
    int e = blockIdx.x * 256 + threadIdx.x;
    if (e >= E) return;
    int ps = atomicAdd(&curs[src[e]], 1);
    perm_src[ps] = e;
    int pd = atomicAdd(&curd[dst[e]], 1);
    perm_dst[pd] = e;
    dpos[e] = pd;
}

// ---------------------------------------------------------------------------
// bf16 MFMA GEMM: C(M,NC) = A(M,K) @ BT(NC,K)^T  [+bias][relu][+res]
// 128x64 tile, 256 threads (4 waves, 2x2), BK=64, XOR-swizzled LDS.
// ---------------------------------------------------------------------------
template <typename OT, bool BIAS, bool RELU, bool RES>
__global__ __launch_bounds__(256) void gemm_mfma(
    const ushort* __restrict__ A, const ushort* __restrict__ BT,
    const float* __restrict__ bias, const float* __restrict__ res,
    OT* __restrict__ C, int M, int K, int NC)
{
    __shared__ char lds[24576];
    char* AsB = lds;            // 128 rows x 128B, XOR swizzled
    char* BsB = lds + 16384;    // 64 rows x 128B

    const int m0 = blockIdx.y * 128;
    const int n0 = blockIdx.x * 64;
    const int t = threadIdx.x;
    const int lane = t & 63, wid = t >> 6;
    const int wm = wid >> 1, wn = wid & 1;
    const int frow = lane & 15, kgrp = lane >> 4;

    f32x4 acc[4][2] = {};

    for (int kk = 0; kk < K; kk += 64) {
#pragma unroll
        for (int it = 0; it < 4; ++it) {            // stage A: 128x64 bf16
            int q = it * 256 + t;
            int r = q >> 3, c8 = (q & 7) * 8;
            int gm = m0 + r;
            short8 v = {};
            if (gm < M) v = *reinterpret_cast<const short8*>(&A[(size_t)gm * K + kk + c8]);
            *reinterpret_cast<short8*>(&AsB[r * 128 + ((c8 * 2) ^ ((r & 7) << 4))]) = v;
        }
#pragma unroll
        for (int it = 0; it < 2; ++it) {            // stage B: 64x64 bf16
            int q = it * 256 + t;
            int r = q >> 3, c8 = (q & 7) * 8;
            short8 v = *reinterpret_cast<const short8*>(&BT[(size_t)(n0 + r) * K + kk + c8]);
            *reinterpret_cast<short8*>(&BsB[r * 128 + ((c8 * 2) ^ ((r & 7) << 4))]) = v;
        }
        __syncthreads();
#pragma unroll
        for (int kp = 0; kp < 2; ++kp) {
            const int koffb = kp * 64 + kgrp * 16;
            short8 b[2];
#pragma unroll
            for (int fn = 0; fn < 2; ++fn) {
                int col = wn * 32 + fn * 16 + frow;
                b[fn] = *reinterpret_cast<const short8*>(&BsB[col * 128 + (koffb ^ ((col & 7) << 4))]);
            }
#pragma unroll
            for (int fm = 0; fm < 4; ++fm) {
                int row = wm * 64 + fm * 16 + frow;
                short8 a = *reinterpret_cast<const short8*>(&AsB[row * 128 + (koffb ^ ((row & 7) << 4))]);
#pragma unroll
                for (int fn = 0; fn < 2; ++fn)
                    acc[fm][fn] = __builtin_amdgcn_mfma_f32_16x16x32_bf16(a, b[fn], acc[fm][fn], 0, 0, 0);
            }
        }
        __syncthreads();
    }

#pragma unroll
    for (int fm = 0; fm < 4; ++fm)
#pragma unroll
        for (int fn = 0; fn < 2; ++fn)
#pragma unroll
            for (int r = 0; r < 4; ++r) {
                int gm = m0 + wm * 64 + fm * 16 + kgrp * 4 + r;   // row = (lane>>4)*4+reg
                int gn = n0 + wn * 32 + fn * 16 + frow;           // col = lane&15
                if (gm >= M) continue;
                float v = acc[fm][fn][r];
                if (BIAS) v += bias[gn];
                if (RELU) v = fmaxf(v, 0.f);
                if (RES) v += res[(size_t)gm * NC + gn];
                stC(&C[(size_t)gm * NC + gn], v);
            }
}

// ---------------------------------------------------------------------------
// Logits per dst node (wave per node). G[d] in registers; loop incoming edges,
// gather feat[src]; multi-head butterfly reduce; den in registers; then
// rescale exb -> a = ex/den in a second (L2-hot) mini-pass.
// ---------------------------------------------------------------------------
__global__ __launch_bounds__(256) void node_logits_kernel(
    const ushort* __restrict__ featbf, const ushort* __restrict__ GVO,
    const int* __restrict__ srcarr, const int* __restrict__ offd,
    const int* __restrict__ perm_dst, float* __restrict__ exb, int N)
{
    int d = (int)((blockIdx.x * 256 + threadIdx.x) >> 6);
    int lane = threadIdx.x & 63;
    if (d >= N) return;

    uint g[8];
#pragma unroll
    for (int h = 0; h < 8; ++h)
        g[h] = *reinterpret_cast<const uint*>(&GVO[(size_t)d * 2048 + h * 128 + 2 * lane]);

    const int lo = offd[d], hi = offd[d + 1];
    float den = 0.f;   // lane h (<8) accumulates den_h

    int e = 0; uint fv = 0;
    if (lo < hi) {
        e = perm_dst[lo];
        fv = reinterpret_cast<const uint*>(featbf)[(size_t)srcarr[e] * 64 + lane];
    }
    for (int i = lo; i < hi; ++i) {
        int ecur = e; uint f = fv;
        if (i + 1 < hi) {                       // software pipeline next gather
            e = perm_dst[i + 1];
            fv = reinterpret_cast<const uint*>(featbf)[(size_t)srcarr[e] * 64 + lane];
        }
        float fx = bf_lo(f), fy = bf_hi(f);
        float p[8];
#pragma unroll
        for (int h = 0; h < 8; ++h)
            p[h] = bf_lo(g[h]) * fx + bf_hi(g[h]) * fy;
        // reduce within 8-lane groups for all heads
#pragma unroll
        for (int h = 0; h < 8; ++h) {
            float v = p[h];
            v += __shfl_xor(v, 1); v += __shfl_xor(v, 2); v += __shfl_xor(v, 4);
            p[h] = v;
        }
        // lane picks head (lane&7), reduce across the 8 groups
        float sel = p[0];
#pragma unroll
        for (int h = 1; h < 8; ++h) sel = ((lane & 7) == h) ? p[h] : sel;
        sel += __shfl_xor(sel, 8); sel += __shfl_xor(sel, 16); sel += __shfl_xor(sel, 32);
        float u = fminf(fmaxf(sel, -5.f), 5.f);
        float ex = __expf(u);
        if (lane < 8) {
            exb[(size_t)ecur * 8 + lane] = ex;
            den += ex;
        }
    }
    float r = 1.f / den;
    for (int i = lo; i < hi; ++i) {
        int e2 = perm_dst[i];
        if (lane < 8) {
            size_t idx = (size_t)e2 * 8 + lane;
            exb[idx] = exb[idx] * r;
        }
    }
}

// ---------------------------------------------------------------------------
// Edge weighted-V (wave per edge, src-sorted order => VO reads L1-hot).
// Writes w = a * VO[src]  (bf16) at the edge's dst-sorted position.
// ---------------------------------------------------------------------------
__global__ __launch_bounds__(256) void edge_w_kernel(
    const ushort* __restrict__ GVO, const int* __restrict__ srcarr,
    const int* __restrict__ perm_src, const int* __restrict__ dposarr,
    const float* __restrict__ exb, ushort* __restrict__ wbuf, int E)
{
    int widx = (int)((blockIdx.x * 256 + threadIdx.x) >> 6);
    int lane = threadIdx.x & 63;
    if (widx >= E) return;
    int e = perm_src[widx];
    int s = srcarr[e];
    int pd = dposarr[e];
    float aval = (lane < 8) ? exb[(size_t)e * 8 + lane] : 0.f;
    float acc0 = 0.f, acc1 = 0.f;
#pragma unroll
    for (int h = 0; h < 8; ++h) {
        float a = __shfl(aval, h);
        uint gv = *reinterpret_cast<const uint*>(&GVO[(size_t)s * 2048 + 1024 + h * 128 + 2 * lane]);
        acc0 += a * bf_lo(gv);
        acc1 += a * bf_hi(gv);
    }
    ushort2 o; o.x = f2bf(acc0); o.y = f2bf(acc1);
    reinterpret_cast<ushort2*>(wbuf)[(size_t)pd * 64 + lane] = o;
}

// ---------------------------------------------------------------------------
// Aggregate contiguous w runs per dst + fused LayerNorm1 (fp32 + bf16 out).
// ---------------------------------------------------------------------------
__global__ __launch_bounds__(256) void agg_ln1_kernel(
    const ushort* __restrict__ wbuf, const int* __restrict__ offd,
    const float* __restrict__ feat, const float* __restrict__ g1,
    const float* __restrict__ b1, float* __restrict__ uh,
    ushort* __restrict__ uhbf, int N)
{
    int d = (int)((blockIdx.x * 256 + threadIdx.x) >> 6);
    int lane = threadIdx.x & 63;
    if (d >= N) return;
    float2 v = reinterpret_cast<const float2*>(feat)[(size_t)d * 64 + lane];
    int lo = offd[d], hi = offd[d + 1];
    for (int i = lo; i < hi; ++i) {
        uint wv = reinterpret_cast<const uint*>(wbuf)[(size_t)i * 64 + lane];
        v.x += bf_lo(wv);
        v.y += bf_hi(wv);
    }
    float sum = v.x + v.y;
#pragma unroll
    for (int off = 32; off; off >>= 1) sum += __shfl_xor(sum, off);
    float mean = sum * (1.f / 128.f);
    float cx = v.x - mean, cy = v.y - mean;
    float vs = cx * cx + cy * cy;
#pragma unroll
    for (int off = 32; off; off >>= 1) vs += __shfl_xor(vs, off);
    float r = rsqrtf(vs * (1.f / 128.f) + 1e-5f);
    float2 gg = reinterpret_cast<const float2*>(g1)[lane];
    float2 bb = reinterpret_cast<const float2*>(b1)[lane];
    float2 o;
    o.x = cx * r * gg.x + bb.x;
    o.y = cy * r * gg.y + bb.y;
    reinterpret_cast<float2*>(uh)[(size_t)d * 64 + lane] = o;
    ushort2 ob; ob.x = f2bf(o.x); ob.y = f2bf(o.y);
    reinterpret_cast<ushort2*>(uhbf)[(size_t)d * 64 + lane] = ob;
}

// ---------------------------------------------------------------------------
// Final LayerNorm
// ---------------------------------------------------------------------------
__global__ __launch_bounds__(256) void ln_kernel(
    const float* __restrict__ x, const float* __restrict__ g,
    const float* __restrict__ b, float* __restrict__ out, int M)
{
    int row = (int)((blockIdx.x * 256 + threadIdx.x) >> 6);
    int lane = threadIdx.x & 63;
    if (row >= M) return;
    float2 v = reinterpret_cast<const float2*>(x)[(size_t)row * 64 + lane];
    float sum = v.x + v.y;
#pragma unroll
    for (int off = 32; off; off >>= 1) sum += __shfl_xor(sum, off);
    float mean = sum * (1.f / 128.f);
    float cx = v.x - mean, cy = v.y - mean;
    float vs = cx * cx + cy * cy;
#pragma unroll
    for (int off = 32; off; off >>= 1) vs += __shfl_xor(vs, off);
    float r = rsqrtf(vs * (1.f / 128.f) + 1e-5f);
    float2 gg = reinterpret_cast<const float2*>(g)[lane];
    float2 bb = reinterpret_cast<const float2*>(b)[lane];
    float2 o;
    o.x = cx * r * gg.x + bb.x;
    o.y = cy * r * gg.y + bb.y;
    reinterpret_cast<float2*>(out)[(size_t)row * 64 + lane] = o;
}

// ---------------------------------------------------------------------------
extern "C" void kernel_launch(void* const* d_in, const int* in_sizes, int n_in,
                              void* d_out, int out_size, void* d_ws, size_t ws_size,
                              hipStream_t stream)
{
    const float* feat = (const float*)d_in[0];
    const int*   src  = (const int*)d_in[1];
    const int*   dst  = (const int*)d_in[2];
    const float* Wq   = (const float*)d_in[3];
    const float* Wk   = (const float*)d_in[4];
    const float* Wv   = (const float*)d_in[5];
    const float* Wo   = (const float*)d_in[6];
    const float* g1   = (const float*)d_in[7];
    const float* b1   = (const float*)d_in[8];
    const float* W1   = (const float*)d_in[9];
    const float* bf1  = (const float*)d_in[10];
    const float* W2   = (const float*)d_in[11];
    const float* bf2  = (const float*)d_in[12];
    const float* g2   = (const float*)d_in[13];
    const float* b2   = (const float*)d_in[14];
    const int N = in_sizes[0] / 128;
    const int E = in_sizes[1];
    float* out = (float*)d_out;

    char* w = (char*)d_ws;
    auto alloc = [&](size_t bytes) {
        char* p = w;
        w += (bytes + 255) & ~(size_t)255;
        return p;
    };
    ushort* MPT      = (ushort*)alloc((size_t)2048 * 128 * 2);
    ushort* W1T      = (ushort*)alloc((size_t)512 * 128 * 2);
    ushort* W2T      = (ushort*)alloc((size_t)128 * 512 * 2);
    ushort* featbf   = (ushort*)alloc((size_t)N * 128 * 2);
    ushort* GVO      = (ushort*)alloc((size_t)N * 2048 * 2);
    float*  exb      = (float*)alloc((size_t)E * 8 * 4);
    int*    cnts     = (int*)alloc((size_t)N * 4);
    int*    cntd     = (int*)alloc((size_t)N * 4);
    int*    offs     = (int*)alloc((size_t)(N + 1) * 4);
    int*    offd     = (int*)alloc((size_t)(N + 1) * 4);
    int*    curs     = (int*)alloc((size_t)N * 4);
    int*    curd     = (int*)alloc((size_t)N * 4);
    int*    perm_src = (int*)alloc((size_t)E * 4);
    int*    perm_dst = (int*)alloc((size_t)E * 4);
    int*    dpos     = (int*)alloc((size_t)E * 4);
    ushort* wbuf     = (ushort*)alloc((size_t)E * 128 * 2);
    float*  uh       = (float*)alloc((size_t)N * 128 * 4);
    ushort* uhbf     = (ushort*)alloc((size_t)N * 128 * 2);
    ushort* f1       = (ushort*)alloc((size_t)N * 512 * 2);
    float*  pre2     = (float*)alloc((size_t)N * 128 * 4);

    hipMemsetAsync(cnts, 0, (size_t)N * 4, stream);
    hipMemsetAsync(cntd, 0, (size_t)N * 4, stream);

    // --- prep (tiny) ---
    f2bf_kernel<<<(N * 128 / 4 + 255) / 256, 256, 0, stream>>>(feat, featbf, N * 128 / 4);
    build_mpt_kernel<<<(128 * 2048 + 255) / 256, 256, 0, stream>>>(Wq, Wk, Wv, Wo, MPT);
    transp_bf_kernel<<<(128 * 512 + 255) / 256, 256, 0, stream>>>(W1, W1T, 128, 512);
    transp_bf_kernel<<<(512 * 128 + 255) / 256, 256, 0, stream>>>(W2, W2T, 512, 128);

    // --- CSR build ---
    int eb = (E + 255) / 256;
    hist_kernel<<<eb, 256, 0, stream>>>(src, dst, cnts, cntd, E);
    scan2_kernel<<<1, 1024, 0, stream>>>(cnts, cntd, offs, offd, curs, curd, N);
    scat_kernel<<<eb, 256, 0, stream>>>(src, dst, curs, curd, perm_src, perm_dst, dpos, E);

    // --- GVO = feat @ [M | P]  (N x 2048, bf16 out) ---
    dim3 gv_grid(2048 / 64, (N + 127) / 128);
    gemm_mfma<ushort, false, false, false><<<gv_grid, 256, 0, stream>>>(
        featbf, MPT, nullptr, nullptr, GVO, N, 128, 2048);

    // --- edge phase ---
    int nwaves_n = (N * 64 + 255) / 256;
    node_logits_kernel<<<nwaves_n, 256, 0, stream>>>(featbf, GVO, src, offd, perm_dst, exb, N);
    int nwaves_e = (E * 64 + 255) / 256;
    edge_w_kernel<<<nwaves_e, 256, 0, stream>>>(GVO, src, perm_src, dpos, exb, wbuf, E);
    agg_ln1_kernel<<<nwaves_n, 256, 0, stream>>>(wbuf, offd, feat, g1, b1, uh, uhbf, N);

    // --- FFN ---
    dim3 f1_grid(512 / 64, (N + 127) / 128);
    gemm_mfma<ushort, true, true, false><<<f1_grid, 256, 0, stream>>>(
        uhbf, W1T, bf1, nullptr, f1, N, 128, 512);
    dim3 f2_grid(128 / 64, (N + 127) / 128);
    gemm_mfma<float, true, false, true><<<f2_grid, 256, 0, stream>>>(
        f1, W2T, bf2, uh, pre2, N, 512, 128);

    ln_kernel<<<nwaves_n, 256, 0, stream>>>(pre2, g2, b2, out, N);
}

// Round 4
// 198.196 us; speedup vs baseline: 1.0923x; 1.0923x over previous
//
#include <hip/hip_runtime.h>

typedef unsigned int uint;
typedef unsigned short ushort;
typedef __attribute__((ext_vector_type(8))) short short8;
typedef __attribute__((ext_vector_type(4))) float f32x4;

#define DEV static __device__ __forceinline__

DEV float bf_lo(uint v) { return __uint_as_float(v << 16); }
DEV float bf_hi(uint v) { return __uint_as_float(v & 0xffff0000u); }
DEV ushort f2bf(float f) {
    uint u = __float_as_uint(f);
    u += 0x7fffu + ((u >> 16) & 1u);   // round-to-nearest-even
    return (ushort)(u >> 16);
}
DEV void stC(float* p, float v) { *p = v; }
DEV void stC(ushort* p, float v) { *p = f2bf(v); }

// VALU-speed cross-lane add via DPP (ctrl must be a literal)
#define DPPADD(v, ctrl) \
    ((v) + __int_as_float(__builtin_amdgcn_mov_dpp(__float_as_int(v), (ctrl), 0xF, 0xF, true)))

// ---------------------------------------------------------------------------
// Fused prep: feat->bf16 | MPT build | W1T | W2T  (blockIdx-range dispatch)
// MPT[c,i]: c<1024 -> (1/sqrt(128))*sum_a Wq[i,h*128+a]*Wk[j,h*128+a]
//           c>=1024 ->              sum_a Wv[i,h*128+a]*Wo[h*128+a,j]
// ---------------------------------------------------------------------------
__global__ __launch_bounds__(256) void prep_kernel(
    const float* __restrict__ feat, ushort* __restrict__ featbf,
    const float* __restrict__ Wq, const float* __restrict__ Wk,
    const float* __restrict__ Wv, const float* __restrict__ Wo,
    ushort* __restrict__ MPT,
    const float* __restrict__ W1, ushort* __restrict__ W1T,
    const float* __restrict__ W2, ushort* __restrict__ W2T, int N)
{
    const int nf = (N * 32 + 255) / 256;   // f2bf blocks (uint4 units)
    int b = blockIdx.x;
    int t = threadIdx.x;
    if (b < nf) {
        int i = b * 256 + t;
        if (i >= N * 32) return;
        float4 v = reinterpret_cast<const float4*>(feat)[i];
        ushort4 o;
        o.x = f2bf(v.x); o.y = f2bf(v.y); o.z = f2bf(v.z); o.w = f2bf(v.w);
        reinterpret_cast<ushort4*>(featbf)[i] = o;
    } else if (b < nf + 1024) {
        int idx = (b - nf) * 256 + t;      // 128*2048
        int i = idx >> 11;
        int c = idx & 2047;
        int h = (c >> 7) & 7;
        int j = c & 127;
        float s = 0.f;
        if (c < 1024) {
            const float* a = Wq + i * 1024 + h * 128;
            const float* bb = Wk + j * 1024 + h * 128;
#pragma unroll 8
            for (int k = 0; k < 128; ++k) s += a[k] * bb[k];
            s *= 0.08838834764831845f;
        } else {
            const float* a = Wv + i * 1024 + h * 128;
            const float* bb = Wo + (h * 128) * 128 + j;
#pragma unroll 8
            for (int k = 0; k < 128; ++k) s += a[k] * bb[(size_t)k * 128];
        }
        MPT[(size_t)c * 128 + i] = f2bf(s);
    } else if (b < nf + 1024 + 256) {
        int tid = (b - nf - 1024) * 256 + t;  // W1: K=128, NC=512
        int n = tid % 512, k = tid / 512;
        W1T[(size_t)n * 128 + k] = f2bf(W1[tid]);
    } else {
        int tid = (b - nf - 1280) * 256 + t;  // W2: K=512, NC=128
        int n = tid % 128, k = tid / 128;
        W2T[(size_t)n * 512 + k] = f2bf(W2[tid]);
    }
}

// ---------------------------------------------------------------------------
// CSR build: histogram -> block scan -> scatter (emits pre-gathered arrays)
// ---------------------------------------------------------------------------
__global__ void hist_kernel(const int* __restrict__ src, const int* __restrict__ dst,
                            int* __restrict__ cnts, int* __restrict__ cntd, int E)
{
    int e = blockIdx.x * 256 + threadIdx.x;
    if (e >= E) return;
    atomicAdd(&cnts[src[e]], 1);
    atomicAdd(&cntd[dst[e]], 1);
}

__global__ __launch_bounds__(1024) void scan2_kernel(
    const int* __restrict__ cnts, const int* __restrict__ cntd,
    int* __restrict__ offs, int* __restrict__ offd,
    int* __restrict__ curs, int* __restrict__ curd, int N)
{
    __shared__ int ls[1024];
    const int t = threadIdx.x;
    const int chunk = (N + 1023) >> 10;
#pragma unroll 1
    for (int a = 0; a < 2; ++a) {
        const int* in = a ? cntd : cnts;
        int* off = a ? offd : offs;
        int* cur = a ? curd : curs;
        int base = t * chunk;
        int s = 0;
        for (int i = 0; i < chunk; ++i) {
            int idx = base + i;
            if (idx < N) s += in[idx];
        }
        ls[t] = s;
        __syncthreads();
        for (int d = 1; d < 1024; d <<= 1) {
            int v = (t >= d) ? ls[t - d] : 0;
            __syncthreads();
            ls[t] += v;
            __syncthreads();
        }
        int run = t ? ls[t - 1] : 0;
        for (int i = 0; i < chunk; ++i) {
            int idx = base + i;
            if (idx < N) {
                off[idx] = run;
                cur[idx] = run;
                run += in[idx];
            }
        }
        if (t == 1023) off[N] = run;
        __syncthreads();
    }
}

__global__ void scat_kernel(const int* __restrict__ src, const int* __restrict__ dst,
                            int* __restrict__ curs, int* __restrict__ curd,
                            int* __restrict__ src_d, int* __restrict__ dst_d,
                            int* __restrict__ src_s, int* __restrict__ pd_s, int E)
{
    int e = blockIdx.x * 256 + threadIdx.x;
    if (e >= E) return;
    int s = src[e], d = dst[e];
    int pd = atomicAdd(&curd[d], 1);
    src_d[pd] = s;
    dst_d[pd] = d;
    int ps = atomicAdd(&curs[s], 1);
    src_s[ps] = s;
    pd_s[ps] = pd;
}

// ---------------------------------------------------------------------------
// bf16 MFMA GEMM: C(M,NC) = A(M,K) @ BT(NC,K)^T  [+bias][relu][+res]
// 128x64 tile, 256 threads (4 waves, 2x2), BK=64, XOR-swizzled LDS.
// ---------------------------------------------------------------------------
template <typename OT, bool BIAS, bool RELU, bool RES>
__global__ __launch_bounds__(256) void gemm_mfma(
    const ushort* __restrict__ A, const ushort* __restrict__ BT,
    const float* __restrict__ bias, const float* __restrict__ res,
    OT* __restrict__ C, int M, int K, int NC)
{
    __shared__ char lds[24576];
    char* AsB = lds;            // 128 rows x 128B, XOR swizzled
    char* BsB = lds + 16384;    // 64 rows x 128B

    const int m0 = blockIdx.y * 128;
    const int n0 = blockIdx.x * 64;
    const int t = threadIdx.x;
    const int lane = t & 63, wid = t >> 6;
    const int wm = wid >> 1, wn = wid & 1;
    const int frow = lane & 15, kgrp = lane >> 4;

    f32x4 acc[4][2] = {};

    for (int kk = 0; kk < K; kk += 64) {
#pragma unroll
        for (int it = 0; it < 4; ++it) {            // stage A: 128x64 bf16
            int q = it * 256 + t;
            int r = q >> 3, c8 = (q & 7) * 8;
            int gm = m0 + r;
            short8 v = {};
            if (gm < M) v = *reinterpret_cast<const short8*>(&A[(size_t)gm * K + kk + c8]);
            *reinterpret_cast<short8*>(&AsB[r * 128 + ((c8 * 2) ^ ((r & 7) << 4))]) = v;
        }
#pragma unroll
        for (int it = 0; it < 2; ++it) {            // stage B: 64x64 bf16
            int q = it * 256 + t;
            int r = q >> 3, c8 = (q & 7) * 8;
            short8 v = *reinterpret_cast<const short8*>(&BT[(size_t)(n0 + r) * K + kk + c8]);
            *reinterpret_cast<short8*>(&BsB[r * 128 + ((c8 * 2) ^ ((r & 7) << 4))]) = v;
        }
        __syncthreads();
#pragma unroll
        for (int kp = 0; kp < 2; ++kp) {
            const int koffb = kp * 64 + kgrp * 16;
            short8 b[2];
#pragma unroll
            for (int fn = 0; fn < 2; ++fn) {
                int col = wn * 32 + fn * 16 + frow;
                b[fn] = *reinterpret_cast<const short8*>(&BsB[col * 128 + (koffb ^ ((col & 7) << 4))]);
            }
#pragma unroll
            for (int fm = 0; fm < 4; ++fm) {
                int row = wm * 64 + fm * 16 + frow;
                short8 a = *reinterpret_cast<const short8*>(&AsB[row * 128 + (koffb ^ ((row & 7) << 4))]);
#pragma unroll
                for (int fn = 0; fn < 2; ++fn)
                    acc[fm][fn] = __builtin_amdgcn_mfma_f32_16x16x32_bf16(a, b[fn], acc[fm][fn], 0, 0, 0);
            }
        }
        __syncthreads();
    }

#pragma unroll
    for (int fm = 0; fm < 4; ++fm)
#pragma unroll
        for (int fn = 0; fn < 2; ++fn)
#pragma unroll
            for (int r = 0; r < 4; ++r) {
                int gm = m0 + wm * 64 + fm * 16 + kgrp * 4 + r;   // row = (lane>>4)*4+reg
                int gn = n0 + wn * 32 + fn * 16 + frow;           // col = lane&15
                if (gm >= M) continue;
                float v = acc[fm][fn][r];
                if (BIAS) v += bias[gn];
                if (RELU) v = fmaxf(v, 0.f);
                if (RES) v += res[(size_t)gm * NC + gn];
                stC(&C[(size_t)gm * NC + gn], v);
            }
}

// ---------------------------------------------------------------------------
// Edge logits: 16 lanes per edge (4 edges/wave), dst-sorted order.
// DPP reduction (VALU) within the 16-lane group. Writes unnormalized exp.
// ---------------------------------------------------------------------------
__global__ __launch_bounds__(256) void edge_logits2_kernel(
    const ushort* __restrict__ featbf, const ushort* __restrict__ GVO,
    const int* __restrict__ src_d, const int* __restrict__ dst_d,
    float* __restrict__ exws, int E)
{
    int w = (int)((blockIdx.x * 256 + threadIdx.x) >> 6);
    int lane = threadIdx.x & 63;
    int el = lane >> 4, li = lane & 15;
    int p = w * 4 + el;
    if (p >= E) return;
    int s = src_d[p], d = dst_d[p];
    uint4 f = reinterpret_cast<const uint4*>(featbf)[(size_t)s * 16 + li];
    const uint4* Grow = reinterpret_cast<const uint4*>(GVO) + (size_t)d * 256 + li;
    float sel = 0.f;
#pragma unroll
    for (int h = 0; h < 8; ++h) {
        uint4 g = Grow[h * 16];
        float pv = bf_lo(g.x) * bf_lo(f.x) + bf_hi(g.x) * bf_hi(f.x);
        pv += bf_lo(g.y) * bf_lo(f.y) + bf_hi(g.y) * bf_hi(f.y);
        pv += bf_lo(g.z) * bf_lo(f.z) + bf_hi(g.z) * bf_hi(f.z);
        pv += bf_lo(g.w) * bf_lo(f.w) + bf_hi(g.w) * bf_hi(f.w);
        pv = DPPADD(pv, 0xB1);   // xor 1 (quad_perm 1,0,3,2)
        pv = DPPADD(pv, 0x4E);   // xor 2 (quad_perm 2,3,0,1)
        pv = DPPADD(pv, 0x141);  // row_half_mirror (xor-4 equiv for sums)
        pv = DPPADD(pv, 0x128);  // row_ror:8 == xor 8 within 16-row
        sel = (li == h) ? pv : sel;
    }
    float u = fminf(fmaxf(sel, -5.f), 5.f);
    float ex = __expf(u);
    if (li < 8) exws[(size_t)p * 8 + li] = ex;
}

// ---------------------------------------------------------------------------
// den: wave per node, lane = eslot*8 + h; 8 edges x 8 heads per iteration.
// Computes 1/den per head, rescales exws in place: exws -> a.
// ---------------------------------------------------------------------------
__global__ __launch_bounds__(256) void den_kernel(
    const int* __restrict__ offd, float* __restrict__ exws, int N)
{
    int d = (int)((blockIdx.x * 256 + threadIdx.x) >> 6);
    int lane = threadIdx.x & 63;
    if (d >= N) return;
    int lo = offd[d], hi = offd[d + 1];
    int es = lane >> 3, h = lane & 7;
    float den = 0.f;
    for (int i = lo + es; i < hi; i += 8)
        den += exws[(size_t)i * 8 + h];
    den += __shfl_xor(den, 8);
    den += __shfl_xor(den, 16);
    den += __shfl_xor(den, 32);
    float r = 1.f / den;
    for (int i = lo + es; i < hi; i += 8)
        exws[(size_t)i * 8 + h] *= r;
}

// ---------------------------------------------------------------------------
// Edge weighted-V (wave per edge, src-sorted => VO reads L1-hot).
// w = sum_h a_h * VO[src,h,:]  (bf16), written at dst-sorted position.
// ---------------------------------------------------------------------------
__global__ __launch_bounds__(256) void edge_w_kernel(
    const ushort* __restrict__ GVO, const int* __restrict__ src_s,
    const int* __restrict__ pd_s, const float* __restrict__ exws,
    ushort* __restrict__ wbuf, int E)
{
    int q = (int)((blockIdx.x * 256 + threadIdx.x) >> 6);
    int lane = threadIdx.x & 63;
    if (q >= E) return;
    int s = src_s[q];
    int pd = pd_s[q];
    float aval = (lane < 8) ? exws[(size_t)pd * 8 + lane] : 0.f;
    float acc0 = 0.f, acc1 = 0.f;
#pragma unroll
    for (int h = 0; h < 8; ++h) {
        float a = __shfl(aval, h);
        uint gv = *reinterpret_cast<const uint*>(&GVO[(size_t)s * 2048 + 1024 + h * 128 + 2 * lane]);
        acc0 += a * bf_lo(gv);
        acc1 += a * bf_hi(gv);
    }
    ushort2 o; o.x = f2bf(acc0); o.y = f2bf(acc1);
    reinterpret_cast<ushort2*>(wbuf)[(size_t)pd * 64 + lane] = o;
}

// ---------------------------------------------------------------------------
// Aggregate contiguous w runs per dst + fused LayerNorm1 (fp32 + bf16 out).
// ---------------------------------------------------------------------------
__global__ __launch_bounds__(256) void agg_ln1_kernel(
    const ushort* __restrict__ wbuf, const int* __restrict__ offd,
    const float* __restrict__ feat, const float* __restrict__ g1,
    const float* __restrict__ b1, float* __restrict__ uh,
    ushort* __restrict__ uhbf, int N)
{
    int d = (int)((blockIdx.x * 256 + threadIdx.x) >> 6);
    int lane = threadIdx.x & 63;
    if (d >= N) return;
    float2 v = reinterpret_cast<const float2*>(feat)[(size_t)d * 64 + lane];
    int lo = offd[d], hi = offd[d + 1];
    for (int i = lo; i < hi; ++i) {
        uint wv = reinterpret_cast<const uint*>(wbuf)[(size_t)i * 64 + lane];
        v.x += bf_lo(wv);
        v.y += bf_hi(wv);
    }
    float sum = v.x + v.y;
#pragma unroll
    for (int off = 32; off; off >>= 1) sum += __shfl_xor(sum, off);
    float mean = sum * (1.f / 128.f);
    float cx = v.x - mean, cy = v.y - mean;
    float vs = cx * cx + cy * cy;
#pragma unroll
    for (int off = 32; off; off >>= 1) vs += __shfl_xor(vs, off);
    float r = rsqrtf(vs * (1.f / 128.f) + 1e-5f);
    float2 gg = reinterpret_cast<const float2*>(g1)[lane];
    float2 bb = reinterpret_cast<const float2*>(b1)[lane];
    float2 o;
    o.x = cx * r * gg.x + bb.x;
    o.y = cy * r * gg.y + bb.y;
    reinterpret_cast<float2*>(uh)[(size_t)d * 64 + lane] = o;
    ushort2 ob; ob.x = f2bf(o.x); ob.y = f2bf(o.y);
    reinterpret_cast<ushort2*>(uhbf)[(size_t)d * 64 + lane] = ob;
}

// ---------------------------------------------------------------------------
// Final LayerNorm
// ---------------------------------------------------------------------------
__global__ __launch_bounds__(256) void ln_kernel(
    const float* __restrict__ x, const float* __restrict__ g,
    const float* __restrict__ b, float* __restrict__ out, int M)
{
    int row = (int)((blockIdx.x * 256 + threadIdx.x) >> 6);
    int lane = threadIdx.x & 63;
    if (row >= M) return;
    float2 v = reinterpret_cast<const float2*>(x)[(size_t)row * 64 + lane];
    float sum = v.x + v.y;
#pragma unroll
    for (int off = 32; off; off >>= 1) sum += __shfl_xor(sum, off);
    float mean = sum * (1.f / 128.f);
    float cx = v.x - mean, cy = v.y - mean;
    float vs = cx * cx + cy * cy;
#pragma unroll
    for (int off = 32; off; off >>= 1) vs += __shfl_xor(vs, off);
    float r = rsqrtf(vs * (1.f / 128.f) + 1e-5f);
    float2 gg = reinterpret_cast<const float2*>(g)[lane];
    float2 bb = reinterpret_cast<const float2*>(b)[lane];
    float2 o;
    o.x = cx * r * gg.x + bb.x;
    o.y = cy * r * gg.y + bb.y;
    reinterpret_cast<float2*>(out)[(size_t)row * 64 + lane] = o;
}

// ---------------------------------------------------------------------------
extern "C" void kernel_launch(void* const* d_in, const int* in_sizes, int n_in,
                              void* d_out, int out_size, void* d_ws, size_t ws_size,
                              hipStream_t stream)
{
    const float* feat = (const float*)d_in[0];
    const int*   src  = (const int*)d_in[1];
    const int*   dst  = (const int*)d_in[2];
    const float* Wq   = (const float*)d_in[3];
    const float* Wk   = (const float*)d_in[4];
    const float* Wv   = (const float*)d_in[5];
    const float* Wo   = (const float*)d_in[6];
    const float* g1   = (const float*)d_in[7];
    const float* b1   = (const float*)d_in[8];
    const float* W1   = (const float*)d_in[9];
    const float* bf1  = (const float*)d_in[10];
    const float* W2   = (const float*)d_in[11];
    const float* bf2  = (const float*)d_in[12];
    const float* g2   = (const float*)d_in[13];
    const float* b2   = (const float*)d_in[14];
    const int N = in_sizes[0] / 128;
    const int E = in_sizes[1];
    float* out = (float*)d_out;

    char* w = (char*)d_ws;
    auto alloc = [&](size_t bytes) {
        char* p = w;
        w += (bytes + 255) & ~(size_t)255;
        return p;
    };
    ushort* MPT    = (ushort*)alloc((size_t)2048 * 128 * 2);
    ushort* W1T    = (ushort*)alloc((size_t)512 * 128 * 2);
    ushort* W2T    = (ushort*)alloc((size_t)128 * 512 * 2);
    ushort* featbf = (ushort*)alloc((size_t)N * 128 * 2);
    ushort* GVO    = (ushort*)alloc((size_t)N * 2048 * 2);
    float*  exws   = (float*)alloc((size_t)E * 8 * 4);
    int*    cnts   = (int*)alloc((size_t)N * 4);
    int*    cntd   = (int*)alloc((size_t)N * 4);
    int*    offs   = (int*)alloc((size_t)(N + 1) * 4);
    int*    offd   = (int*)alloc((size_t)(N + 1) * 4);
    int*    curs   = (int*)alloc((size_t)N * 4);
    int*    curd   = (int*)alloc((size_t)N * 4);
    int*    src_d  = (int*)alloc((size_t)E * 4);
    int*    dst_d  = (int*)alloc((size_t)E * 4);
    int*    src_s  = (int*)alloc((size_t)E * 4);
    int*    pd_s   = (int*)alloc((size_t)E * 4);
    ushort* wbuf   = (ushort*)alloc((size_t)E * 128 * 2);
    float*  uh     = (float*)alloc((size_t)N * 128 * 4);
    ushort* uhbf   = (ushort*)alloc((size_t)N * 128 * 2);
    ushort* f1     = (ushort*)alloc((size_t)N * 512 * 2);
    float*  pre2   = (float*)alloc((size_t)N * 128 * 4);

    hipMemsetAsync(cnts, 0, (size_t)N * 4, stream);
    hipMemsetAsync(cntd, 0, (size_t)N * 4, stream);

    // --- fused prep ---
    int nf = (N * 32 + 255) / 256;
    prep_kernel<<<nf + 1024 + 256 + 256, 256, 0, stream>>>(
        feat, featbf, Wq, Wk, Wv, Wo, MPT, W1, W1T, W2, W2T, N);

    // --- CSR build ---
    int eb = (E + 255) / 256;
    hist_kernel<<<eb, 256, 0, stream>>>(src, dst, cnts, cntd, E);
    scan2_kernel<<<1, 1024, 0, stream>>>(cnts, cntd, offs, offd, curs, curd, N);
    scat_kernel<<<eb, 256, 0, stream>>>(src, dst, curs, curd, src_d, dst_d, src_s, pd_s, E);

    // --- GVO = feat @ [M | P]  (N x 2048, bf16 out) ---
    dim3 gv_grid(2048 / 64, (N + 127) / 128);
    gemm_mfma<ushort, false, false, false><<<gv_grid, 256, 0, stream>>>(
        featbf, MPT, nullptr, nullptr, GVO, N, 128, 2048);

    // --- edge phase ---
    edge_logits2_kernel<<<(E + 15) / 16, 256, 0, stream>>>(featbf, GVO, src_d, dst_d, exws, E);
    int nwaves_n = (N * 64 + 255) / 256;
    den_kernel<<<nwaves_n, 256, 0, stream>>>(offd, exws, N);
    int nwaves_e = (E * 64 + 255) / 256;
    edge_w_kernel<<<nwaves_e, 256, 0, stream>>>(GVO, src_s, pd_s, exws, wbuf, E);
    agg_ln1_kernel<<<nwaves_n, 256, 0, stream>>>(wbuf, offd, feat, g1, b1, uh, uhbf, N);

    // --- FFN ---
    dim3 f1_grid(512 / 64, (N + 127) / 128);
    gemm_mfma<ushort, true, true, false><<<f1_grid, 256, 0, stream>>>(
        uhbf, W1T, bf1, nullptr, f1, N, 128, 512);
    dim3 f2_grid(128 / 64, (N + 127) / 128);
    gemm_mfma<float, true, false, true><<<f2_grid, 256, 0, stream>>>(
        f1, W2T, bf2, uh, pre2, N, 512, 128);

    ln_kernel<<<nwaves_n, 256, 0, stream>>>(pre2, g2, b2, out, N);
}

// Round 5
// 171.460 us; speedup vs baseline: 1.2626x; 1.1559x over previous
//
#include <hip/hip_runtime.h>

typedef unsigned int uint;
typedef unsigned short ushort;
typedef __attribute__((ext_vector_type(8))) short short8;
typedef __attribute__((ext_vector_type(4))) float f32x4;

#define DEV static __device__ __forceinline__

DEV float bf_lo(uint v) { return __uint_as_float(v << 16); }
DEV float bf_hi(uint v) { return __uint_as_float(v & 0xffff0000u); }
DEV ushort f2bf(float f) {
    uint u = __float_as_uint(f);
    u += 0x7fffu + ((u >> 16) & 1u);   // round-to-nearest-even
    return (ushort)(u >> 16);
}
DEV void stC(float* p, float v) { *p = v; }
DEV void stC(ushort* p, float v) { *p = f2bf(v); }

// VALU-speed cross-lane add via DPP (ctrl must be a literal)
#define DPPADD(v, ctrl) \
    ((v) + __int_as_float(__builtin_amdgcn_mov_dpp(__float_as_int(v), (ctrl), 0xF, 0xF, true)))

// ---------------------------------------------------------------------------
// feat fp32 -> bf16 (uint4 granules)
// ---------------------------------------------------------------------------
__global__ __launch_bounds__(256) void f2bf_kernel(
    const float* __restrict__ in, ushort* __restrict__ out, int n4)
{
    int i = blockIdx.x * 256 + threadIdx.x;
    if (i >= n4) return;
    float4 v = reinterpret_cast<const float4*>(in)[i];
    ushort4 o;
    o.x = f2bf(v.x); o.y = f2bf(v.y); o.z = f2bf(v.z); o.w = f2bf(v.w);
    reinterpret_cast<ushort4*>(out)[i] = o;
}

// ---------------------------------------------------------------------------
// Tiled transpose: in[R][C] fp32 -> out[C][R] (fp32 or bf16). 64x64 tiles,
// coalesced loads and stores via padded LDS tile. Grid = (R/64)*(C/64).
// ---------------------------------------------------------------------------
template <typename OT>
__global__ __launch_bounds__(256) void transp_kernel(
    const float* __restrict__ in, OT* __restrict__ out, int R, int C)
{
    __shared__ float tile[64][65];
    const int nbx = C >> 6;
    const int bx = blockIdx.x % nbx, by = blockIdx.x / nbx;
    const int t = threadIdx.x;
#pragma unroll
    for (int it = 0; it < 4; ++it) {
        int idx = it * 256 + t;
        int rr = idx >> 4, cc4 = (idx & 15) * 4;
        float4 v = *reinterpret_cast<const float4*>(in + (size_t)(by * 64 + rr) * C + bx * 64 + cc4);
        tile[cc4][rr] = v.x; tile[cc4 + 1][rr] = v.y;
        tile[cc4 + 2][rr] = v.z; tile[cc4 + 3][rr] = v.w;
    }
    __syncthreads();
#pragma unroll
    for (int it = 0; it < 4; ++it) {
        int idx = it * 256 + t;
        int cc = idx >> 4, rr4 = (idx & 15) * 4;
        OT* po = out + (size_t)(bx * 64 + cc) * R + by * 64 + rr4;
        if constexpr (__is_same(OT, float)) {
            float4 o = { tile[cc][rr4], tile[cc][rr4 + 1], tile[cc][rr4 + 2], tile[cc][rr4 + 3] };
            *reinterpret_cast<float4*>(po) = o;
        } else {
            ushort4 o = { f2bf(tile[cc][rr4]), f2bf(tile[cc][rr4 + 1]),
                          f2bf(tile[cc][rr4 + 2]), f2bf(tile[cc][rr4 + 3]) };
            *reinterpret_cast<ushort4*>(po) = o;
        }
    }
}

// ---------------------------------------------------------------------------
// MPT build via MFMA. 16 workgroups: part = blockIdx>>3, h = blockIdx&7.
//  part0: C[j][i] = scale * sum_a Wk[j,h*128+a] * Wq[i,h*128+a]   (= M_h[i][j])
//  part1: C[j][i] =         sum_a WoT[j,h*128+a] * Wv[i,h*128+a]  (= P_h[i][j])
// MPT[(part*1024 + h*128 + j) * 128 + i] = bf16(C[j][i])
// ---------------------------------------------------------------------------
__global__ __launch_bounds__(256) void mpt_mfma_kernel(
    const float* __restrict__ Wq, const float* __restrict__ Wk,
    const float* __restrict__ Wv, const float* __restrict__ WoT,
    ushort* __restrict__ MPT)
{
    __shared__ char lds[65536];
    char* As = lds;            // 128 rows(j) x 256B (128 bf16), XOR swizzled
    char* Bs = lds + 32768;    // 128 rows(i) x 256B

    const int part = blockIdx.x >> 3, h = blockIdx.x & 7;
    const int t = threadIdx.x;
    const int lane = t & 63, w = t >> 6;
    const int frow = lane & 15, kgrp = lane >> 4;

    const float* Asrc = part ? WoT : Wk;
    const float* Bsrc = part ? Wv : Wq;
    const float ascale = part ? 1.f : 0.08838834764831845f;

#pragma unroll
    for (int it = 0; it < 16; ++it) {
        int idx = it * 256 + t;
        int r = idx >> 5, c4 = (idx & 31) * 4;
        size_t goff = (size_t)r * 1024 + h * 128 + c4;
        float4 va = *reinterpret_cast<const float4*>(Asrc + goff);
        ushort4 ua = { f2bf(va.x * ascale), f2bf(va.y * ascale),
                       f2bf(va.z * ascale), f2bf(va.w * ascale) };
        *reinterpret_cast<ushort4*>(&As[r * 256 + ((c4 * 2) ^ ((r & 7) << 4))]) = ua;
        float4 vb = *reinterpret_cast<const float4*>(Bsrc + goff);
        ushort4 ub = { f2bf(vb.x), f2bf(vb.y), f2bf(vb.z), f2bf(vb.w) };
        *reinterpret_cast<ushort4*>(&Bs[r * 256 + ((c4 * 2) ^ ((r & 7) << 4))]) = ub;
    }
    __syncthreads();

    f32x4 acc[2][8] = {};
#pragma unroll
    for (int ks = 0; ks < 4; ++ks) {
        int koff = ks * 64 + kgrp * 16;
        short8 b[8];
#pragma unroll
        for (int fn = 0; fn < 8; ++fn) {
            int col = fn * 16 + frow;
            b[fn] = *reinterpret_cast<const short8*>(&Bs[col * 256 + (koff ^ ((col & 7) << 4))]);
        }
#pragma unroll
        for (int fm = 0; fm < 2; ++fm) {
            int row = w * 32 + fm * 16 + frow;
            short8 a = *reinterpret_cast<const short8*>(&As[row * 256 + (koff ^ ((row & 7) << 4))]);
#pragma unroll
            for (int fn = 0; fn < 8; ++fn)
                acc[fm][fn] = __builtin_amdgcn_mfma_f32_16x16x32_bf16(a, b[fn], acc[fm][fn], 0, 0, 0);
        }
    }

    const size_t base = ((size_t)part * 1024 + h * 128) * 128;
#pragma unroll
    for (int fm = 0; fm < 2; ++fm)
#pragma unroll
        for (int fn = 0; fn < 8; ++fn)
#pragma unroll
            for (int r = 0; r < 4; ++r) {
                int j = w * 32 + fm * 16 + kgrp * 4 + r;
                int i = fn * 16 + frow;
                MPT[base + (size_t)j * 128 + i] = f2bf(acc[fm][fn][r]);
            }
}

// ---------------------------------------------------------------------------
// CSR build: histogram -> block scan -> scatter (emits pre-gathered arrays)
// ---------------------------------------------------------------------------
__global__ void hist_kernel(const int* __restrict__ src, const int* __restrict__ dst,
                            int* __restrict__ cnts, int* __restrict__ cntd, int E)
{
    int e = blockIdx.x * 256 + threadIdx.x;
    if (e >= E) return;
    atomicAdd(&cnts[src[e]], 1);
    atomicAdd(&cntd[dst[e]], 1);
}

__global__ __launch_bounds__(1024) void scan2_kernel(
    const int* __restrict__ cnts, const int* __restrict__ cntd,
    int* __restrict__ offs, int* __restrict__ offd,
    int* __restrict__ curs, int* __restrict__ curd, int N)
{
    __shared__ int ls[1024];
    const int t = threadIdx.x;
    const int chunk = (N + 1023) >> 10;
#pragma unroll 1
    for (int a = 0; a < 2; ++a) {
        const int* in = a ? cntd : cnts;
        int* off = a ? offd : offs;
        int* cur = a ? curd : curs;
        int base = t * chunk;
        int s = 0;
        for (int i = 0; i < chunk; ++i) {
            int idx = base + i;
            if (idx < N) s += in[idx];
        }
        ls[t] = s;
        __syncthreads();
        for (int d = 1; d < 1024; d <<= 1) {
            int v = (t >= d) ? ls[t - d] : 0;
            __syncthreads();
            ls[t] += v;
            __syncthreads();
        }
        int run = t ? ls[t - 1] : 0;
        for (int i = 0; i < chunk; ++i) {
            int idx = base + i;
            if (idx < N) {
                off[idx] = run;
                cur[idx] = run;
                run += in[idx];
            }
        }
        if (t == 1023) off[N] = run;
        __syncthreads();
    }
}

__global__ void scat_kernel(const int* __restrict__ src, const int* __restrict__ dst,
                            int* __restrict__ curs, int* __restrict__ curd,
                            int* __restrict__ src_d, int* __restrict__ dst_d,
                            int* __restrict__ src_s, int* __restrict__ pd_s, int E)
{
    int e = blockIdx.x * 256 + threadIdx.x;
    if (e >= E) return;
    int s = src[e], d = dst[e];
    int pd = atomicAdd(&curd[d], 1);
    src_d[pd] = s;
    dst_d[pd] = d;
    int ps = atomicAdd(&curs[s], 1);
    src_s[ps] = s;
    pd_s[ps] = pd;
}

// ---------------------------------------------------------------------------
// bf16 MFMA GEMM: C(M,NC) = A(M,K) @ BT(NC,K)^T  [+bias][relu][+res]
// 128x64 tile, 256 threads (4 waves, 2x2), BK=64, XOR-swizzled LDS.
// ---------------------------------------------------------------------------
template <typename OT, bool BIAS, bool RELU, bool RES>
__global__ __launch_bounds__(256) void gemm_mfma(
    const ushort* __restrict__ A, const ushort* __restrict__ BT,
    const float* __restrict__ bias, const float* __restrict__ res,
    OT* __restrict__ C, int M, int K, int NC)
{
    __shared__ char lds[24576];
    char* AsB = lds;            // 128 rows x 128B, XOR swizzled
    char* BsB = lds + 16384;    // 64 rows x 128B

    const int m0 = blockIdx.y * 128;
    const int n0 = blockIdx.x * 64;
    const int t = threadIdx.x;
    const int lane = t & 63, wid = t >> 6;
    const int wm = wid >> 1, wn = wid & 1;
    const int frow = lane & 15, kgrp = lane >> 4;

    f32x4 acc[4][2] = {};

    for (int kk = 0; kk < K; kk += 64) {
#pragma unroll
        for (int it = 0; it < 4; ++it) {            // stage A: 128x64 bf16
            int q = it * 256 + t;
            int r = q >> 3, c8 = (q & 7) * 8;
            int gm = m0 + r;
            short8 v = {};
            if (gm < M) v = *reinterpret_cast<const short8*>(&A[(size_t)gm * K + kk + c8]);
            *reinterpret_cast<short8*>(&AsB[r * 128 + ((c8 * 2) ^ ((r & 7) << 4))]) = v;
        }
#pragma unroll
        for (int it = 0; it < 2; ++it) {            // stage B: 64x64 bf16
            int q = it * 256 + t;
            int r = q >> 3, c8 = (q & 7) * 8;
            short8 v = *reinterpret_cast<const short8*>(&BT[(size_t)(n0 + r) * K + kk + c8]);
            *reinterpret_cast<short8*>(&BsB[r * 128 + ((c8 * 2) ^ ((r & 7) << 4))]) = v;
        }
        __syncthreads();
#pragma unroll
        for (int kp = 0; kp < 2; ++kp) {
            const int koffb = kp * 64 + kgrp * 16;
            short8 b[2];
#pragma unroll
            for (int fn = 0; fn < 2; ++fn) {
                int col = wn * 32 + fn * 16 + frow;
                b[fn] = *reinterpret_cast<const short8*>(&BsB[col * 128 + (koffb ^ ((col & 7) << 4))]);
            }
#pragma unroll
            for (int fm = 0; fm < 4; ++fm) {
                int row = wm * 64 + fm * 16 + frow;
                short8 a = *reinterpret_cast<const short8*>(&AsB[row * 128 + (koffb ^ ((row & 7) << 4))]);
#pragma unroll
                for (int fn = 0; fn < 2; ++fn)
                    acc[fm][fn] = __builtin_amdgcn_mfma_f32_16x16x32_bf16(a, b[fn], acc[fm][fn], 0, 0, 0);
            }
        }
        __syncthreads();
    }

#pragma unroll
    for (int fm = 0; fm < 4; ++fm)
#pragma unroll
        for (int fn = 0; fn < 2; ++fn)
#pragma unroll
            for (int r = 0; r < 4; ++r) {
                int gm = m0 + wm * 64 + fm * 16 + kgrp * 4 + r;   // row = (lane>>4)*4+reg
                int gn = n0 + wn * 32 + fn * 16 + frow;           // col = lane&15
                if (gm >= M) continue;
                float v = acc[fm][fn][r];
                if (BIAS) v += bias[gn];
                if (RELU) v = fmaxf(v, 0.f);
                if (RES) v += res[(size_t)gm * NC + gn];
                stC(&C[(size_t)gm * NC + gn], v);
            }
}

// ---------------------------------------------------------------------------
// Edge logits: 16 lanes per edge (4 edges/wave), dst-sorted order.
// DPP reduction (VALU) within the 16-lane group. Writes unnormalized exp.
// ---------------------------------------------------------------------------
__global__ __launch_bounds__(256) void edge_logits2_kernel(
    const ushort* __restrict__ featbf, const ushort* __restrict__ GVO,
    const int* __restrict__ src_d, const int* __restrict__ dst_d,
    float* __restrict__ exws, int E)
{
    int w = (int)((blockIdx.x * 256 + threadIdx.x) >> 6);
    int lane = threadIdx.x & 63;
    int el = lane >> 4, li = lane & 15;
    int p = w * 4 + el;
    if (p >= E) return;
    int s = src_d[p], d = dst_d[p];
    uint4 f = reinterpret_cast<const uint4*>(featbf)[(size_t)s * 16 + li];
    const uint4* Grow = reinterpret_cast<const uint4*>(GVO) + (size_t)d * 256 + li;
    float sel = 0.f;
#pragma unroll
    for (int h = 0; h < 8; ++h) {
        uint4 g = Grow[h * 16];
        float pv = bf_lo(g.x) * bf_lo(f.x) + bf_hi(g.x) * bf_hi(f.x);
        pv += bf_lo(g.y) * bf_lo(f.y) + bf_hi(g.y) * bf_hi(f.y);
        pv += bf_lo(g.z) * bf_lo(f.z) + bf_hi(g.z) * bf_hi(f.z);
        pv += bf_lo(g.w) * bf_lo(f.w) + bf_hi(g.w) * bf_hi(f.w);
        pv = DPPADD(pv, 0xB1);   // xor 1
        pv = DPPADD(pv, 0x4E);   // xor 2
        pv = DPPADD(pv, 0x141);  // row_half_mirror
        pv = DPPADD(pv, 0x128);  // row_ror:8
        sel = (li == h) ? pv : sel;
    }
    float u = fminf(fmaxf(sel, -5.f), 5.f);
    float ex = __expf(u);
    if (li < 8) exws[(size_t)p * 8 + li] = ex;
}

// ---------------------------------------------------------------------------
// den: wave per node, lane = eslot*8 + h; 8 edges x 8 heads per iteration.
// Computes 1/den per head, rescales exws in place: exws -> a.
// ---------------------------------------------------------------------------
__global__ __launch_bounds__(256) void den_kernel(
    const int* __restrict__ offd, float* __restrict__ exws, int N)
{
    int d = (int)((blockIdx.x * 256 + threadIdx.x) >> 6);
    int lane = threadIdx.x & 63;
    if (d >= N) return;
    int lo = offd[d], hi = offd[d + 1];
    int es = lane >> 3, h = lane & 7;
    float den = 0.f;
    for (int i = lo + es; i < hi; i += 8)
        den += exws[(size_t)i * 8 + h];
    den += __shfl_xor(den, 8);
    den += __shfl_xor(den, 16);
    den += __shfl_xor(den, 32);
    float r = 1.f / den;
    for (int i = lo + es; i < hi; i += 8)
        exws[(size_t)i * 8 + h] *= r;
}

// ---------------------------------------------------------------------------
// Edge weighted-V (wave per edge, src-sorted => VO reads L1-hot).
// w = sum_h a_h * VO[src,h,:]  (bf16), written at dst-sorted position.
// ---------------------------------------------------------------------------
__global__ __launch_bounds__(256) void edge_w_kernel(
    const ushort* __restrict__ GVO, const int* __restrict__ src_s,
    const int* __restrict__ pd_s, const float* __restrict__ exws,
    ushort* __restrict__ wbuf, int E)
{
    int q = (int)((blockIdx.x * 256 + threadIdx.x) >> 6);
    int lane = threadIdx.x & 63;
    if (q >= E) return;
    int s = src_s[q];
    int pd = pd_s[q];
    float aval = (lane < 8) ? exws[(size_t)pd * 8 + lane] : 0.f;
    float acc0 = 0.f, acc1 = 0.f;
#pragma unroll
    for (int h = 0; h < 8; ++h) {
        float a = __shfl(aval, h);
        uint gv = *reinterpret_cast<const uint*>(&GVO[(size_t)s * 2048 + 1024 + h * 128 + 2 * lane]);
        acc0 += a * bf_lo(gv);
        acc1 += a * bf_hi(gv);
    }
    ushort2 o; o.x = f2bf(acc0); o.y = f2bf(acc1);
    reinterpret_cast<ushort2*>(wbuf)[(size_t)pd * 64 + lane] = o;
}

// ---------------------------------------------------------------------------
// Aggregate contiguous w runs per dst + fused LayerNorm1 (fp32 + bf16 out).
// ---------------------------------------------------------------------------
__global__ __launch_bounds__(256) void agg_ln1_kernel(
    const ushort* __restrict__ wbuf, const int* __restrict__ offd,
    const float* __restrict__ feat, const float* __restrict__ g1,
    const float* __restrict__ b1, float* __restrict__ uh,
    ushort* __restrict__ uhbf, int N)
{
    int d = (int)((blockIdx.x * 256 + threadIdx.x) >> 6);
    int lane = threadIdx.x & 63;
    if (d >= N) return;
    float2 v = reinterpret_cast<const float2*>(feat)[(size_t)d * 64 + lane];
    int lo = offd[d], hi = offd[d + 1];
    for (int i = lo; i < hi; ++i) {
        uint wv = reinterpret_cast<const uint*>(wbuf)[(size_t)i * 64 + lane];
        v.x += bf_lo(wv);
        v.y += bf_hi(wv);
    }
    float sum = v.x + v.y;
#pragma unroll
    for (int off = 32; off; off >>= 1) sum += __shfl_xor(sum, off);
    float mean = sum * (1.f / 128.f);
    float cx = v.x - mean, cy = v.y - mean;
    float vs = cx * cx + cy * cy;
#pragma unroll
    for (int off = 32; off; off >>= 1) vs += __shfl_xor(vs, off);
    float r = rsqrtf(vs * (1.f / 128.f) + 1e-5f);
    float2 gg = reinterpret_cast<const float2*>(g1)[lane];
    float2 bb = reinterpret_cast<const float2*>(b1)[lane];
    float2 o;
    o.x = cx * r * gg.x + bb.x;
    o.y = cy * r * gg.y + bb.y;
    reinterpret_cast<float2*>(uh)[(size_t)d * 64 + lane] = o;
    ushort2 ob; ob.x = f2bf(o.x); ob.y = f2bf(o.y);
    reinterpret_cast<ushort2*>(uhbf)[(size_t)d * 64 + lane] = ob;
}

// ---------------------------------------------------------------------------
// Final LayerNorm
// ---------------------------------------------------------------------------
__global__ __launch_bounds__(256) void ln_kernel(
    const float* __restrict__ x, const float* __restrict__ g,
    const float* __restrict__ b, float* __restrict__ out, int M)
{
    int row = (int)((blockIdx.x * 256 + threadIdx.x) >> 6);
    int lane = threadIdx.x & 63;
    if (row >= M) return;
    float2 v = reinterpret_cast<const float2*>(x)[(size_t)row * 64 + lane];
    float sum = v.x + v.y;
#pragma unroll
    for (int off = 32; off; off >>= 1) sum += __shfl_xor(sum, off);
    float mean = sum * (1.f / 128.f);
    float cx = v.x - mean, cy = v.y - mean;
    float vs = cx * cx + cy * cy;
#pragma unroll
    for (int off = 32; off; off >>= 1) vs += __shfl_xor(vs, off);
    float r = rsqrtf(vs * (1.f / 128.f) + 1e-5f);
    float2 gg = reinterpret_cast<const float2*>(g)[lane];
    float2 bb = reinterpret_cast<const float2*>(b)[lane];
    float2 o;
    o.x = cx * r * gg.x + bb.x;
    o.y = cy * r * gg.y + bb.y;
    reinterpret_cast<float2*>(out)[(size_t)row * 64 + lane] = o;
}

// ---------------------------------------------------------------------------
extern "C" void kernel_launch(void* const* d_in, const int* in_sizes, int n_in,
                              void* d_out, int out_size, void* d_ws, size_t ws_size,
                              hipStream_t stream)
{
    const float* feat = (const float*)d_in[0];
    const int*   src  = (const int*)d_in[1];
    const int*   dst  = (const int*)d_in[2];
    const float* Wq   = (const float*)d_in[3];
    const float* Wk   = (const float*)d_in[4];
    const float* Wv   = (const float*)d_in[5];
    const float* Wo   = (const float*)d_in[6];
    const float* g1   = (const float*)d_in[7];
    const float* b1   = (const float*)d_in[8];
    const float* W1   = (const float*)d_in[9];
    const float* bf1  = (const float*)d_in[10];
    const float* W2   = (const float*)d_in[11];
    const float* bf2  = (const float*)d_in[12];
    const float* g2   = (const float*)d_in[13];
    const float* b2   = (const float*)d_in[14];
    const int N = in_sizes[0] / 128;
    const int E = in_sizes[1];
    float* out = (float*)d_out;

    char* w = (char*)d_ws;
    auto alloc = [&](size_t bytes) {
        char* p = w;
        w += (bytes + 255) & ~(size_t)255;
        return p;
    };
    ushort* MPT    = (ushort*)alloc((size_t)2048 * 128 * 2);
    float*  WoT    = (float*)alloc((size_t)128 * 1024 * 4);
    ushort* W1T    = (ushort*)alloc((size_t)512 * 128 * 2);
    ushort* W2T    = (ushort*)alloc((size_t)128 * 512 * 2);
    ushort* featbf = (ushort*)alloc((size_t)N * 128 * 2);
    ushort* GVO    = (ushort*)alloc((size_t)N * 2048 * 2);
    float*  exws   = (float*)alloc((size_t)E * 8 * 4);
    int*    cnts   = (int*)alloc((size_t)N * 4);
    int*    cntd   = (int*)alloc((size_t)N * 4);
    int*    offs   = (int*)alloc((size_t)(N + 1) * 4);
    int*    offd   = (int*)alloc((size_t)(N + 1) * 4);
    int*    curs   = (int*)alloc((size_t)N * 4);
    int*    curd   = (int*)alloc((size_t)N * 4);
    int*    src_d  = (int*)alloc((size_t)E * 4);
    int*    dst_d  = (int*)alloc((size_t)E * 4);
    int*    src_s  = (int*)alloc((size_t)E * 4);
    int*    pd_s   = (int*)alloc((size_t)E * 4);
    ushort* wbuf   = (ushort*)alloc((size_t)E * 128 * 2);
    float*  uh     = (float*)alloc((size_t)N * 128 * 4);
    ushort* uhbf   = (ushort*)alloc((size_t)N * 128 * 2);
    ushort* f1     = (ushort*)alloc((size_t)N * 512 * 2);
    float*  pre2   = (float*)alloc((size_t)N * 128 * 4);

    hipMemsetAsync(cnts, 0, (size_t)N * 4, stream);
    hipMemsetAsync(cntd, 0, (size_t)N * 4, stream);

    // --- weight prep: transposes + MFMA MPT build ---
    transp_kernel<float><<<(1024 / 64) * (128 / 64), 256, 0, stream>>>(Wo, WoT, 1024, 128);
    transp_kernel<ushort><<<(128 / 64) * (512 / 64), 256, 0, stream>>>(W1, W1T, 128, 512);
    transp_kernel<ushort><<<(512 / 64) * (128 / 64), 256, 0, stream>>>(W2, W2T, 512, 128);
    f2bf_kernel<<<(N * 32 + 255) / 256, 256, 0, stream>>>(feat, featbf, N * 32);
    mpt_mfma_kernel<<<16, 256, 0, stream>>>(Wq, Wk, Wv, WoT, MPT);

    // --- CSR build ---
    int eb = (E + 255) / 256;
    hist_kernel<<<eb, 256, 0, stream>>>(src, dst, cnts, cntd, E);
    scan2_kernel<<<1, 1024, 0, stream>>>(cnts, cntd, offs, offd, curs, curd, N);
    scat_kernel<<<eb, 256, 0, stream>>>(src, dst, curs, curd, src_d, dst_d, src_s, pd_s, E);

    // --- GVO = feat @ [M | P]  (N x 2048, bf16 out) ---
    dim3 gv_grid(2048 / 64, (N + 127) / 128);
    gemm_mfma<ushort, false, false, false><<<gv_grid, 256, 0, stream>>>(
        featbf, MPT, nullptr, nullptr, GVO, N, 128, 2048);

    // --- edge phase ---
    edge_logits2_kernel<<<(E + 15) / 16, 256, 0, stream>>>(featbf, GVO, src_d, dst_d, exws, E);
    int nwaves_n = (N * 64 + 255) / 256;
    den_kernel<<<nwaves_n, 256, 0, stream>>>(offd, exws, N);
    int nwaves_e = (E * 64 + 255) / 256;
    edge_w_kernel<<<nwaves_e, 256, 0, stream>>>(GVO, src_s, pd_s, exws, wbuf, E);
    agg_ln1_kernel<<<nwaves_n, 256, 0, stream>>>(wbuf, offd, feat, g1, b1, uh, uhbf, N);

    // --- FFN ---
    dim3 f1_grid(512 / 64, (N + 127) / 128);
    gemm_mfma<ushort, true, true, false><<<f1_grid, 256, 0, stream>>>(
        uhbf, W1T, bf1, nullptr, f1, N, 128, 512);
    dim3 f2_grid(128 / 64, (N + 127) / 128);
    gemm_mfma<float, true, false, true><<<f2_grid, 256, 0, stream>>>(
        f1, W2T, bf2, uh, pre2, N, 512, 128);

    ln_kernel<<<nwaves_n, 256, 0, stream>>>(pre2, g2, b2, out, N);
}

// Round 6
// 166.698 us; speedup vs baseline: 1.2987x; 1.0286x over previous
//
#include <hip/hip_runtime.h>

typedef unsigned int uint;
typedef unsigned short ushort;
typedef __attribute__((ext_vector_type(8))) short short8;
typedef __attribute__((ext_vector_type(4))) float f32x4;

#define DEV static __device__ __forceinline__

DEV float bf_lo(uint v) { return __uint_as_float(v << 16); }
DEV float bf_hi(uint v) { return __uint_as_float(v & 0xffff0000u); }
DEV ushort f2bf(float f) {
    uint u = __float_as_uint(f);
    u += 0x7fffu + ((u >> 16) & 1u);   // round-to-nearest-even
    return (ushort)(u >> 16);
}
DEV void stC(float* p, float v) { *p = v; }
DEV void stC(ushort* p, float v) { *p = f2bf(v); }

// VALU-speed cross-lane add via DPP (ctrl must be a literal)
#define DPPADD(v, ctrl) \
    ((v) + __int_as_float(__builtin_amdgcn_mov_dpp(__float_as_int(v), (ctrl), 0xF, 0xF, true)))

// ---------------------------------------------------------------------------
// 64x64 tiled transpose body (in fp32 [R][C] -> out [C][R] fp32/bf16)
// ---------------------------------------------------------------------------
template <typename OT>
DEV void transp_body(float (*tile)[65], const float* __restrict__ in,
                     OT* __restrict__ out, int R, int C, int bid, int t)
{
    const int nbx = C >> 6;
    const int bx = bid % nbx, by = bid / nbx;
#pragma unroll
    for (int it = 0; it < 4; ++it) {
        int idx = it * 256 + t;
        int rr = idx >> 4, cc4 = (idx & 15) * 4;
        float4 v = *reinterpret_cast<const float4*>(in + (size_t)(by * 64 + rr) * C + bx * 64 + cc4);
        tile[cc4][rr] = v.x; tile[cc4 + 1][rr] = v.y;
        tile[cc4 + 2][rr] = v.z; tile[cc4 + 3][rr] = v.w;
    }
    __syncthreads();
#pragma unroll
    for (int it = 0; it < 4; ++it) {
        int idx = it * 256 + t;
        int cc = idx >> 4, rr4 = (idx & 15) * 4;
        OT* po = out + (size_t)(bx * 64 + cc) * R + by * 64 + rr4;
        if constexpr (__is_same(OT, float)) {
            float4 o = { tile[cc][rr4], tile[cc][rr4 + 1], tile[cc][rr4 + 2], tile[cc][rr4 + 3] };
            *reinterpret_cast<float4*>(po) = o;
        } else {
            ushort4 o = { f2bf(tile[cc][rr4]), f2bf(tile[cc][rr4 + 1]),
                          f2bf(tile[cc][rr4 + 2]), f2bf(tile[cc][rr4 + 3]) };
            *reinterpret_cast<ushort4*>(po) = o;
        }
    }
}

// ---------------------------------------------------------------------------
// Fused prep: [f2bf feat] [transp Wo fp32] [transp W1 bf16] [transp W2 bf16]
//             [CSR histogram]   via blockIdx-range dispatch
// ---------------------------------------------------------------------------
__global__ __launch_bounds__(256) void prep0_kernel(
    const float* __restrict__ feat, ushort* __restrict__ featbf,
    const float* __restrict__ Wo, float* __restrict__ WoT,
    const float* __restrict__ W1, ushort* __restrict__ W1T,
    const float* __restrict__ W2, ushort* __restrict__ W2T,
    const int* __restrict__ src, const int* __restrict__ dst,
    int* __restrict__ cnts, int* __restrict__ cntd, int N, int E)
{
    __shared__ float tile[64][65];
    const int nf = (N * 32 + 255) / 256;
    const int b = blockIdx.x, t = threadIdx.x;
    if (b < nf) {
        int i = b * 256 + t;
        if (i >= N * 32) return;
        float4 v = reinterpret_cast<const float4*>(feat)[i];
        ushort4 o;
        o.x = f2bf(v.x); o.y = f2bf(v.y); o.z = f2bf(v.z); o.w = f2bf(v.w);
        reinterpret_cast<ushort4*>(featbf)[i] = o;
    } else if (b < nf + 32) {
        transp_body<float>(tile, Wo, WoT, 1024, 128, b - nf, t);
    } else if (b < nf + 48) {
        transp_body<ushort>(tile, W1, W1T, 128, 512, b - nf - 32, t);
    } else if (b < nf + 64) {
        transp_body<ushort>(tile, W2, W2T, 512, 128, b - nf - 48, t);
    } else {
        int e = (b - nf - 64) * 256 + t;
        if (e >= E) return;
        atomicAdd(&cnts[src[e]], 1);
        atomicAdd(&cntd[dst[e]], 1);
    }
}

// ---------------------------------------------------------------------------
// MPT build via MFMA. 16 workgroups: part = blockIdx>>3, h = blockIdx&7.
//  part0: C[j][i] = scale * sum_a Wk[j,h*128+a] * Wq[i,h*128+a]   (= M_h[i][j])
//  part1: C[j][i] =         sum_a WoT[j,h*128+a] * Wv[i,h*128+a]  (= P_h[i][j])
// MPT[(part*1024 + h*128 + j) * 128 + i] = bf16(C[j][i])
// ---------------------------------------------------------------------------
__global__ __launch_bounds__(256) void mpt_mfma_kernel(
    const float* __restrict__ Wq, const float* __restrict__ Wk,
    const float* __restrict__ Wv, const float* __restrict__ WoT,
    ushort* __restrict__ MPT)
{
    __shared__ char lds[65536];
    char* As = lds;            // 128 rows(j) x 256B (128 bf16), XOR swizzled
    char* Bs = lds + 32768;    // 128 rows(i) x 256B

    const int part = blockIdx.x >> 3, h = blockIdx.x & 7;
    const int t = threadIdx.x;
    const int lane = t & 63, w = t >> 6;
    const int frow = lane & 15, kgrp = lane >> 4;

    const float* Asrc = part ? WoT : Wk;
    const float* Bsrc = part ? Wv : Wq;
    const float ascale = part ? 1.f : 0.08838834764831845f;

#pragma unroll
    for (int it = 0; it < 16; ++it) {
        int idx = it * 256 + t;
        int r = idx >> 5, c4 = (idx & 31) * 4;
        size_t goff = (size_t)r * 1024 + h * 128 + c4;
        float4 va = *reinterpret_cast<const float4*>(Asrc + goff);
        ushort4 ua = { f2bf(va.x * ascale), f2bf(va.y * ascale),
                       f2bf(va.z * ascale), f2bf(va.w * ascale) };
        *reinterpret_cast<ushort4*>(&As[r * 256 + ((c4 * 2) ^ ((r & 7) << 4))]) = ua;
        float4 vb = *reinterpret_cast<const float4*>(Bsrc + goff);
        ushort4 ub = { f2bf(vb.x), f2bf(vb.y), f2bf(vb.z), f2bf(vb.w) };
        *reinterpret_cast<ushort4*>(&Bs[r * 256 + ((c4 * 2) ^ ((r & 7) << 4))]) = ub;
    }
    __syncthreads();

    f32x4 acc[2][8] = {};
#pragma unroll
    for (int ks = 0; ks < 4; ++ks) {
        int koff = ks * 64 + kgrp * 16;
        short8 b[8];
#pragma unroll
        for (int fn = 0; fn < 8; ++fn) {
            int col = fn * 16 + frow;
            b[fn] = *reinterpret_cast<const short8*>(&Bs[col * 256 + (koff ^ ((col & 7) << 4))]);
        }
#pragma unroll
        for (int fm = 0; fm < 2; ++fm) {
            int row = w * 32 + fm * 16 + frow;
            short8 a = *reinterpret_cast<const short8*>(&As[row * 256 + (koff ^ ((row & 7) << 4))]);
#pragma unroll
            for (int fn = 0; fn < 8; ++fn)
                acc[fm][fn] = __builtin_amdgcn_mfma_f32_16x16x32_bf16(a, b[fn], acc[fm][fn], 0, 0, 0);
        }
    }

    const size_t base = ((size_t)part * 1024 + h * 128) * 128;
#pragma unroll
    for (int fm = 0; fm < 2; ++fm)
#pragma unroll
        for (int fn = 0; fn < 8; ++fn)
#pragma unroll
            for (int r = 0; r < 4; ++r) {
                int j = w * 32 + fm * 16 + kgrp * 4 + r;
                int i = fn * 16 + frow;
                MPT[base + (size_t)j * 128 + i] = f2bf(acc[fm][fn][r]);
            }
}

// ---------------------------------------------------------------------------
// CSR scan + scatter
// ---------------------------------------------------------------------------
__global__ __launch_bounds__(1024) void scan2_kernel(
    const int* __restrict__ cnts, const int* __restrict__ cntd,
    int* __restrict__ offs, int* __restrict__ offd,
    int* __restrict__ curs, int* __restrict__ curd, int N)
{
    __shared__ int ls[1024];
    const int t = threadIdx.x;
    const int chunk = (N + 1023) >> 10;
#pragma unroll 1
    for (int a = 0; a < 2; ++a) {
        const int* in = a ? cntd : cnts;
        int* off = a ? offd : offs;
        int* cur = a ? curd : curs;
        int base = t * chunk;
        int s = 0;
        for (int i = 0; i < chunk; ++i) {
            int idx = base + i;
            if (idx < N) s += in[idx];
        }
        ls[t] = s;
        __syncthreads();
        for (int d = 1; d < 1024; d <<= 1) {
            int v = (t >= d) ? ls[t - d] : 0;
            __syncthreads();
            ls[t] += v;
            __syncthreads();
        }
        int run = t ? ls[t - 1] : 0;
        for (int i = 0; i < chunk; ++i) {
            int idx = base + i;
            if (idx < N) {
                off[idx] = run;
                cur[idx] = run;
                run += in[idx];
            }
        }
        if (t == 1023) off[N] = run;
        __syncthreads();
    }
}

__global__ void scat_kernel(const int* __restrict__ src, const int* __restrict__ dst,
                            int* __restrict__ curs, int* __restrict__ curd,
                            int* __restrict__ src_d, int* __restrict__ dst_d,
                            int* __restrict__ src_s, int* __restrict__ pd_s, int E)
{
    int e = blockIdx.x * 256 + threadIdx.x;
    if (e >= E) return;
    int s = src[e], d = dst[e];
    int pd = atomicAdd(&curd[d], 1);
    src_d[pd] = s;
    dst_d[pd] = d;
    int ps = atomicAdd(&curs[s], 1);
    src_s[ps] = s;
    pd_s[ps] = pd;
}

// ---------------------------------------------------------------------------
// bf16 MFMA GEMM: C(M,NC) = A(M,K) @ BT(NC,K)^T  [+bias][relu][+res]
// 128 x (NTILE*64) tile, 256 threads (4 waves, 2x2), BK=64, XOR-swizzled LDS.
// ---------------------------------------------------------------------------
template <int NTILE, typename OT, bool BIAS, bool RELU, bool RES>
__global__ __launch_bounds__(256) void gemm_mfma(
    const ushort* __restrict__ A, const ushort* __restrict__ BT,
    const float* __restrict__ bias, const float* __restrict__ res,
    OT* __restrict__ C, int M, int K, int NC)
{
    constexpr int FN = NTILE * 2;        // b-frags per wave
    constexpr int WN = NTILE * 32;       // wave n-width
    __shared__ char lds[16384 + NTILE * 8192];
    char* AsB = lds;                     // 128 rows x 128B, XOR swizzled
    char* BsB = lds + 16384;             // NTILE*64 rows x 128B

    const int m0 = blockIdx.y * 128;
    const int n0 = blockIdx.x * (NTILE * 64);
    const int t = threadIdx.x;
    const int lane = t & 63, wid = t >> 6;
    const int wm = wid >> 1, wn = wid & 1;
    const int frow = lane & 15, kgrp = lane >> 4;

    f32x4 acc[4][FN] = {};

    for (int kk = 0; kk < K; kk += 64) {
#pragma unroll
        for (int it = 0; it < 4; ++it) {            // stage A: 128x64 bf16
            int q = it * 256 + t;
            int r = q >> 3, c8 = (q & 7) * 8;
            int gm = m0 + r;
            short8 v = {};
            if (gm < M) v = *reinterpret_cast<const short8*>(&A[(size_t)gm * K + kk + c8]);
            *reinterpret_cast<short8*>(&AsB[r * 128 + ((c8 * 2) ^ ((r & 7) << 4))]) = v;
        }
#pragma unroll
        for (int it = 0; it < 2 * NTILE; ++it) {    // stage B: (NTILE*64)x64 bf16
            int q = it * 256 + t;
            int r = q >> 3, c8 = (q & 7) * 8;
            short8 v = *reinterpret_cast<const short8*>(&BT[(size_t)(n0 + r) * K + kk + c8]);
            *reinterpret_cast<short8*>(&BsB[r * 128 + ((c8 * 2) ^ ((r & 7) << 4))]) = v;
        }
        __syncthreads();
#pragma unroll
        for (int kp = 0; kp < 2; ++kp) {
            const int koffb = kp * 64 + kgrp * 16;
            short8 b[FN];
#pragma unroll
            for (int fn = 0; fn < FN; ++fn) {
                int col = wn * WN + fn * 16 + frow;
                b[fn] = *reinterpret_cast<const short8*>(&BsB[col * 128 + (koffb ^ ((col & 7) << 4))]);
            }
#pragma unroll
            for (int fm = 0; fm < 4; ++fm) {
                int row = wm * 64 + fm * 16 + frow;
                short8 a = *reinterpret_cast<const short8*>(&AsB[row * 128 + (koffb ^ ((row & 7) << 4))]);
#pragma unroll
                for (int fn = 0; fn < FN; ++fn)
                    acc[fm][fn] = __builtin_amdgcn_mfma_f32_16x16x32_bf16(a, b[fn], acc[fm][fn], 0, 0, 0);
            }
        }
        __syncthreads();
    }

#pragma unroll
    for (int fm = 0; fm < 4; ++fm)
#pragma unroll
        for (int fn = 0; fn < FN; ++fn)
#pragma unroll
            for (int r = 0; r < 4; ++r) {
                int gm = m0 + wm * 64 + fm * 16 + kgrp * 4 + r;   // row = (lane>>4)*4+reg
                int gn = n0 + wn * WN + fn * 16 + frow;           // col = lane&15
                if (gm >= M) continue;
                float v = acc[fm][fn][r];
                if (BIAS) v += bias[gn];
                if (RELU) v = fmaxf(v, 0.f);
                if (RES) v += res[(size_t)gm * NC + gn];
                stC(&C[(size_t)gm * NC + gn], v);
            }
}

// ---------------------------------------------------------------------------
// Edge logits: 16 lanes per edge (4 edges/wave), dst-sorted order.
// DPP reduction (VALU) within the 16-lane group. Writes unnormalized exp.
// ---------------------------------------------------------------------------
__global__ __launch_bounds__(256) void edge_logits2_kernel(
    const ushort* __restrict__ featbf, const ushort* __restrict__ GVO,
    const int* __restrict__ src_d, const int* __restrict__ dst_d,
    float* __restrict__ exws, int E)
{
    int w = (int)((blockIdx.x * 256 + threadIdx.x) >> 6);
    int lane = threadIdx.x & 63;
    int el = lane >> 4, li = lane & 15;
    int p = w * 4 + el;
    if (p >= E) return;
    int s = src_d[p], d = dst_d[p];
    uint4 f = reinterpret_cast<const uint4*>(featbf)[(size_t)s * 16 + li];
    const uint4* Grow = reinterpret_cast<const uint4*>(GVO) + (size_t)d * 256 + li;
    float sel = 0.f;
#pragma unroll
    for (int h = 0; h < 8; ++h) {
        uint4 g = Grow[h * 16];
        float pv = bf_lo(g.x) * bf_lo(f.x) + bf_hi(g.x) * bf_hi(f.x);
        pv += bf_lo(g.y) * bf_lo(f.y) + bf_hi(g.y) * bf_hi(f.y);
        pv += bf_lo(g.z) * bf_lo(f.z) + bf_hi(g.z) * bf_hi(f.z);
        pv += bf_lo(g.w) * bf_lo(f.w) + bf_hi(g.w) * bf_hi(f.w);
        pv = DPPADD(pv, 0xB1);   // xor 1
        pv = DPPADD(pv, 0x4E);   // xor 2
        pv = DPPADD(pv, 0x141);  // row_half_mirror
        pv = DPPADD(pv, 0x128);  // row_ror:8
        sel = (li == h) ? pv : sel;
    }
    float u = fminf(fmaxf(sel, -5.f), 5.f);
    float ex = __expf(u);
    if (li < 8) exws[(size_t)p * 8 + li] = ex;
}

// ---------------------------------------------------------------------------
// den: wave per node, lane = eslot*8 + h; rescales exws in place -> a.
// ---------------------------------------------------------------------------
__global__ __launch_bounds__(256) void den_kernel(
    const int* __restrict__ offd, float* __restrict__ exws, int N)
{
    int d = (int)((blockIdx.x * 256 + threadIdx.x) >> 6);
    int lane = threadIdx.x & 63;
    if (d >= N) return;
    int lo = offd[d], hi = offd[d + 1];
    int es = lane >> 3, h = lane & 7;
    float den = 0.f;
    for (int i = lo + es; i < hi; i += 8)
        den += exws[(size_t)i * 8 + h];
    den += __shfl_xor(den, 8);
    den += __shfl_xor(den, 16);
    den += __shfl_xor(den, 32);
    float r = 1.f / den;
    for (int i = lo + es; i < hi; i += 8)
        exws[(size_t)i * 8 + h] *= r;
}

// ---------------------------------------------------------------------------
// Edge weighted-V (wave per edge, src-sorted => VO reads L1-hot).
// w = sum_h a_h * VO[src,h,:]  (bf16), written at dst-sorted position.
// ---------------------------------------------------------------------------
__global__ __launch_bounds__(256) void edge_w_kernel(
    const ushort* __restrict__ GVO, const int* __restrict__ src_s,
    const int* __restrict__ pd_s, const float* __restrict__ exws,
    ushort* __restrict__ wbuf, int E)
{
    int q = (int)((blockIdx.x * 256 + threadIdx.x) >> 6);
    int lane = threadIdx.x & 63;
    if (q >= E) return;
    int s = src_s[q];
    int pd = pd_s[q];
    float aval = (lane < 8) ? exws[(size_t)pd * 8 + lane] : 0.f;
    float acc0 = 0.f, acc1 = 0.f;
#pragma unroll
    for (int h = 0; h < 8; ++h) {
        float a = __shfl(aval, h);
        uint gv = *reinterpret_cast<const uint*>(&GVO[(size_t)s * 2048 + 1024 + h * 128 + 2 * lane]);
        acc0 += a * bf_lo(gv);
        acc1 += a * bf_hi(gv);
    }
    ushort2 o; o.x = f2bf(acc0); o.y = f2bf(acc1);
    reinterpret_cast<ushort2*>(wbuf)[(size_t)pd * 64 + lane] = o;
}

// ---------------------------------------------------------------------------
// Aggregate contiguous w runs per dst + fused LayerNorm1 (fp32 + bf16 out).
// ---------------------------------------------------------------------------
__global__ __launch_bounds__(256) void agg_ln1_kernel(
    const ushort* __restrict__ wbuf, const int* __restrict__ offd,
    const float* __restrict__ feat, const float* __restrict__ g1,
    const float* __restrict__ b1, float* __restrict__ uh,
    ushort* __restrict__ uhbf, int N)
{
    int d = (int)((blockIdx.x * 256 + threadIdx.x) >> 6);
    int lane = threadIdx.x & 63;
    if (d >= N) return;
    float2 v = reinterpret_cast<const float2*>(feat)[(size_t)d * 64 + lane];
    int lo = offd[d], hi = offd[d + 1];
    for (int i = lo; i < hi; ++i) {
        uint wv = reinterpret_cast<const uint*>(wbuf)[(size_t)i * 64 + lane];
        v.x += bf_lo(wv);
        v.y += bf_hi(wv);
    }
    float sum = v.x + v.y;
#pragma unroll
    for (int off = 32; off; off >>= 1) sum += __shfl_xor(sum, off);
    float mean = sum * (1.f / 128.f);
    float cx = v.x - mean, cy = v.y - mean;
    float vs = cx * cx + cy * cy;
#pragma unroll
    for (int off = 32; off; off >>= 1) vs += __shfl_xor(vs, off);
    float r = rsqrtf(vs * (1.f / 128.f) + 1e-5f);
    float2 gg = reinterpret_cast<const float2*>(g1)[lane];
    float2 bb = reinterpret_cast<const float2*>(b1)[lane];
    float2 o;
    o.x = cx * r * gg.x + bb.x;
    o.y = cy * r * gg.y + bb.y;
    reinterpret_cast<float2*>(uh)[(size_t)d * 64 + lane] = o;
    ushort2 ob; ob.x = f2bf(o.x); ob.y = f2bf(o.y);
    reinterpret_cast<ushort2*>(uhbf)[(size_t)d * 64 + lane] = ob;
}

// ---------------------------------------------------------------------------
// Final LayerNorm
// ---------------------------------------------------------------------------
__global__ __launch_bounds__(256) void ln_kernel(
    const float* __restrict__ x, const float* __restrict__ g,
    const float* __restrict__ b, float* __restrict__ out, int M)
{
    int row = (int)((blockIdx.x * 256 + threadIdx.x) >> 6);
    int lane = threadIdx.x & 63;
    if (row >= M) return;
    float2 v = reinterpret_cast<const float2*>(x)[(size_t)row * 64 + lane];
    float sum = v.x + v.y;
#pragma unroll
    for (int off = 32; off; off >>= 1) sum += __shfl_xor(sum, off);
    float mean = sum * (1.f / 128.f);
    float cx = v.x - mean, cy = v.y - mean;
    float vs = cx * cx + cy * cy;
#pragma unroll
    for (int off = 32; off; off >>= 1) vs += __shfl_xor(vs, off);
    float r = rsqrtf(vs * (1.f / 128.f) + 1e-5f);
    float2 gg = reinterpret_cast<const float2*>(g)[lane];
    float2 bb = reinterpret_cast<const float2*>(b)[lane];
    float2 o;
    o.x = cx * r * gg.x + bb.x;
    o.y = cy * r * gg.y + bb.y;
    reinterpret_cast<float2*>(out)[(size_t)row * 64 + lane] = o;
}

// ---------------------------------------------------------------------------
extern "C" void kernel_launch(void* const* d_in, const int* in_sizes, int n_in,
                              void* d_out, int out_size, void* d_ws, size_t ws_size,
                              hipStream_t stream)
{
    const float* feat = (const float*)d_in[0];
    const int*   src  = (const int*)d_in[1];
    const int*   dst  = (const int*)d_in[2];
    const float* Wq   = (const float*)d_in[3];
    const float* Wk   = (const float*)d_in[4];
    const float* Wv   = (const float*)d_in[5];
    const float* Wo   = (const float*)d_in[6];
    const float* g1   = (const float*)d_in[7];
    const float* b1   = (const float*)d_in[8];
    const float* W1   = (const float*)d_in[9];
    const float* bf1  = (const float*)d_in[10];
    const float* W2   = (const float*)d_in[11];
    const float* bf2  = (const float*)d_in[12];
    const float* g2   = (const float*)d_in[13];
    const float* b2   = (const float*)d_in[14];
    const int N = in_sizes[0] / 128;
    const int E = in_sizes[1];
    float* out = (float*)d_out;

    char* w = (char*)d_ws;
    auto alloc = [&](size_t bytes) {
        char* p = w;
        w += (bytes + 255) & ~(size_t)255;
        return p;
    };
    ushort* MPT    = (ushort*)alloc((size_t)2048 * 128 * 2);
    float*  WoT    = (float*)alloc((size_t)128 * 1024 * 4);
    ushort* W1T    = (ushort*)alloc((size_t)512 * 128 * 2);
    ushort* W2T    = (ushort*)alloc((size_t)128 * 512 * 2);
    ushort* featbf = (ushort*)alloc((size_t)N * 128 * 2);
    ushort* GVO    = (ushort*)alloc((size_t)N * 2048 * 2);
    float*  exws   = (float*)alloc((size_t)E * 8 * 4);
    int*    cnt2   = (int*)alloc((size_t)2 * N * 4);   // [cnts | cntd]
    int*    cnts   = cnt2;
    int*    cntd   = cnt2 + N;
    int*    offs   = (int*)alloc((size_t)(N + 1) * 4);
    int*    offd   = (int*)alloc((size_t)(N + 1) * 4);
    int*    curs   = (int*)alloc((size_t)N * 4);
    int*    curd   = (int*)alloc((size_t)N * 4);
    int*    src_d  = (int*)alloc((size_t)E * 4);
    int*    dst_d  = (int*)alloc((size_t)E * 4);
    int*    src_s  = (int*)alloc((size_t)E * 4);
    int*    pd_s   = (int*)alloc((size_t)E * 4);
    ushort* wbuf   = (ushort*)alloc((size_t)E * 128 * 2);
    float*  uh     = (float*)alloc((size_t)N * 128 * 4);
    ushort* uhbf   = (ushort*)alloc((size_t)N * 128 * 2);
    ushort* f1     = (ushort*)alloc((size_t)N * 512 * 2);
    float*  pre2   = (float*)alloc((size_t)N * 128 * 4);

    hipMemsetAsync(cnt2, 0, (size_t)2 * N * 4, stream);

    // --- fused prep: f2bf + 3 transposes + CSR histogram ---
    int nf = (N * 32 + 255) / 256;
    int eb = (E + 255) / 256;
    prep0_kernel<<<nf + 64 + eb, 256, 0, stream>>>(
        feat, featbf, Wo, WoT, W1, W1T, W2, W2T, src, dst, cnts, cntd, N, E);

    // --- CSR scan + scatter, MPT build ---
    scan2_kernel<<<1, 1024, 0, stream>>>(cnts, cntd, offs, offd, curs, curd, N);
    scat_kernel<<<eb, 256, 0, stream>>>(src, dst, curs, curd, src_d, dst_d, src_s, pd_s, E);
    mpt_mfma_kernel<<<16, 256, 0, stream>>>(Wq, Wk, Wv, WoT, MPT);

    // --- GVO = feat @ [M | P]  (N x 2048, bf16 out), 128x128 tile ---
    dim3 gv_grid(2048 / 128, (N + 127) / 128);
    gemm_mfma<2, ushort, false, false, false><<<gv_grid, 256, 0, stream>>>(
        featbf, MPT, nullptr, nullptr, GVO, N, 128, 2048);

    // --- edge phase ---
    edge_logits2_kernel<<<(E + 15) / 16, 256, 0, stream>>>(featbf, GVO, src_d, dst_d, exws, E);
    int nwaves_n = (N * 64 + 255) / 256;
    den_kernel<<<nwaves_n, 256, 0, stream>>>(offd, exws, N);
    int nwaves_e = (E * 64 + 255) / 256;
    edge_w_kernel<<<nwaves_e, 256, 0, stream>>>(GVO, src_s, pd_s, exws, wbuf, E);
    agg_ln1_kernel<<<nwaves_n, 256, 0, stream>>>(wbuf, offd, feat, g1, b1, uh, uhbf, N);

    // --- FFN ---
    dim3 f1_grid(512 / 128, (N + 127) / 128);
    gemm_mfma<2, ushort, true, true, false><<<f1_grid, 256, 0, stream>>>(
        uhbf, W1T, bf1, nullptr, f1, N, 128, 512);
    dim3 f2_grid(128 / 64, (N + 127) / 128);
    gemm_mfma<1, float, true, false, true><<<f2_grid, 256, 0, stream>>>(
        f1, W2T, bf2, uh, pre2, N, 512, 128);

    ln_kernel<<<nwaves_n, 256, 0, stream>>>(pre2, g2, b2, out, N);
}

// Round 7
// 153.927 us; speedup vs baseline: 1.4064x; 1.0830x over previous
//
#include <hip/hip_runtime.h>

typedef unsigned int uint;
typedef unsigned short ushort;
typedef __attribute__((ext_vector_type(8))) short short8;
typedef __attribute__((ext_vector_type(4))) float f32x4;

#define DEV static __device__ __forceinline__

DEV float bf_lo(uint v) { return __uint_as_float(v << 16); }
DEV float bf_hi(uint v) { return __uint_as_float(v & 0xffff0000u); }
DEV ushort f2bf(float f) {
    uint u = __float_as_uint(f);
    u += 0x7fffu + ((u >> 16) & 1u);   // round-to-nearest-even
    return (ushort)(u >> 16);
}
DEV void stC(float* p, float v) { *p = v; }
DEV void stC(ushort* p, float v) { *p = f2bf(v); }

// VALU-speed cross-lane add via DPP (ctrl must be a literal)
#define DPPADD(v, ctrl) \
    ((v) + __int_as_float(__builtin_amdgcn_mov_dpp(__float_as_int(v), (ctrl), 0xF, 0xF, true)))

// ---------------------------------------------------------------------------
// 64x64 tiled transpose body (in fp32 [R][C] -> out [C][R] fp32/bf16)
// ---------------------------------------------------------------------------
template <typename OT>
DEV void transp_body(float (*tile)[65], const float* __restrict__ in,
                     OT* __restrict__ out, int R, int C, int bid, int t)
{
    const int nbx = C >> 6;
    const int bx = bid % nbx, by = bid / nbx;
#pragma unroll
    for (int it = 0; it < 4; ++it) {
        int idx = it * 256 + t;
        int rr = idx >> 4, cc4 = (idx & 15) * 4;
        float4 v = *reinterpret_cast<const float4*>(in + (size_t)(by * 64 + rr) * C + bx * 64 + cc4);
        tile[cc4][rr] = v.x; tile[cc4 + 1][rr] = v.y;
        tile[cc4 + 2][rr] = v.z; tile[cc4 + 3][rr] = v.w;
    }
    __syncthreads();
#pragma unroll
    for (int it = 0; it < 4; ++it) {
        int idx = it * 256 + t;
        int cc = idx >> 4, rr4 = (idx & 15) * 4;
        OT* po = out + (size_t)(bx * 64 + cc) * R + by * 64 + rr4;
        if constexpr (__is_same(OT, float)) {
            float4 o = { tile[cc][rr4], tile[cc][rr4 + 1], tile[cc][rr4 + 2], tile[cc][rr4 + 3] };
            *reinterpret_cast<float4*>(po) = o;
        } else {
            ushort4 o = { f2bf(tile[cc][rr4]), f2bf(tile[cc][rr4 + 1]),
                          f2bf(tile[cc][rr4 + 2]), f2bf(tile[cc][rr4 + 3]) };
            *reinterpret_cast<ushort4*>(po) = o;
        }
    }
}

// ---------------------------------------------------------------------------
// Fused prep: [f2bf feat] [transp Wo fp32] [transp W1 bf16] [transp W2 bf16]
//             [CSR dst-histogram]   via blockIdx-range dispatch
// ---------------------------------------------------------------------------
__global__ __launch_bounds__(256) void prep0_kernel(
    const float* __restrict__ feat, ushort* __restrict__ featbf,
    const float* __restrict__ Wo, float* __restrict__ WoT,
    const float* __restrict__ W1, ushort* __restrict__ W1T,
    const float* __restrict__ W2, ushort* __restrict__ W2T,
    const int* __restrict__ dst, int* __restrict__ cntd, int N, int E)
{
    __shared__ float tile[64][65];
    const int nf = (N * 32 + 255) / 256;
    const int b = blockIdx.x, t = threadIdx.x;
    if (b < nf) {
        int i = b * 256 + t;
        if (i >= N * 32) return;
        float4 v = reinterpret_cast<const float4*>(feat)[i];
        ushort4 o;
        o.x = f2bf(v.x); o.y = f2bf(v.y); o.z = f2bf(v.z); o.w = f2bf(v.w);
        reinterpret_cast<ushort4*>(featbf)[i] = o;
    } else if (b < nf + 32) {
        transp_body<float>(tile, Wo, WoT, 1024, 128, b - nf, t);
    } else if (b < nf + 48) {
        transp_body<ushort>(tile, W1, W1T, 128, 512, b - nf - 32, t);
    } else if (b < nf + 64) {
        transp_body<ushort>(tile, W2, W2T, 512, 128, b - nf - 48, t);
    } else {
        int e = (b - nf - 64) * 256 + t;
        if (e >= E) return;
        atomicAdd(&cntd[dst[e]], 1);
    }
}

// ---------------------------------------------------------------------------
// MPT build via MFMA. 16 workgroups: part = blockIdx>>3, h = blockIdx&7.
//  part0: C[j][i] = scale * sum_a Wk[j,h*128+a] * Wq[i,h*128+a]   (= M_h[i][j])
//  part1: C[j][i] =         sum_a WoT[j,h*128+a] * Wv[i,h*128+a]  (= P_h[i][j])
// MPT[(part*1024 + h*128 + j) * 128 + i] = bf16(C[j][i])
// ---------------------------------------------------------------------------
__global__ __launch_bounds__(256) void mpt_mfma_kernel(
    const float* __restrict__ Wq, const float* __restrict__ Wk,
    const float* __restrict__ Wv, const float* __restrict__ WoT,
    ushort* __restrict__ MPT)
{
    __shared__ char lds[65536];
    char* As = lds;            // 128 rows(j) x 256B (128 bf16), XOR swizzled
    char* Bs = lds + 32768;    // 128 rows(i) x 256B

    const int part = blockIdx.x >> 3, h = blockIdx.x & 7;
    const int t = threadIdx.x;
    const int lane = t & 63, w = t >> 6;
    const int frow = lane & 15, kgrp = lane >> 4;

    const float* Asrc = part ? WoT : Wk;
    const float* Bsrc = part ? Wv : Wq;
    const float ascale = part ? 1.f : 0.08838834764831845f;

#pragma unroll
    for (int it = 0; it < 16; ++it) {
        int idx = it * 256 + t;
        int r = idx >> 5, c4 = (idx & 31) * 4;
        size_t goff = (size_t)r * 1024 + h * 128 + c4;
        float4 va = *reinterpret_cast<const float4*>(Asrc + goff);
        ushort4 ua = { f2bf(va.x * ascale), f2bf(va.y * ascale),
                       f2bf(va.z * ascale), f2bf(va.w * ascale) };
        *reinterpret_cast<ushort4*>(&As[r * 256 + ((c4 * 2) ^ ((r & 7) << 4))]) = ua;
        float4 vb = *reinterpret_cast<const float4*>(Bsrc + goff);
        ushort4 ub = { f2bf(vb.x), f2bf(vb.y), f2bf(vb.z), f2bf(vb.w) };
        *reinterpret_cast<ushort4*>(&Bs[r * 256 + ((c4 * 2) ^ ((r & 7) << 4))]) = ub;
    }
    __syncthreads();

    f32x4 acc[2][8] = {};
#pragma unroll
    for (int ks = 0; ks < 4; ++ks) {
        int koff = ks * 64 + kgrp * 16;
        short8 b[8];
#pragma unroll
        for (int fn = 0; fn < 8; ++fn) {
            int col = fn * 16 + frow;
            b[fn] = *reinterpret_cast<const short8*>(&Bs[col * 256 + (koff ^ ((col & 7) << 4))]);
        }
#pragma unroll
        for (int fm = 0; fm < 2; ++fm) {
            int row = w * 32 + fm * 16 + frow;
            short8 a = *reinterpret_cast<const short8*>(&As[row * 256 + (koff ^ ((row & 7) << 4))]);
#pragma unroll
            for (int fn = 0; fn < 8; ++fn)
                acc[fm][fn] = __builtin_amdgcn_mfma_f32_16x16x32_bf16(a, b[fn], acc[fm][fn], 0, 0, 0);
        }
    }

    const size_t base = ((size_t)part * 1024 + h * 128) * 128;
#pragma unroll
    for (int fm = 0; fm < 2; ++fm)
#pragma unroll
        for (int fn = 0; fn < 8; ++fn)
#pragma unroll
            for (int r = 0; r < 4; ++r) {
                int j = w * 32 + fm * 16 + kgrp * 4 + r;
                int i = fn * 16 + frow;
                MPT[base + (size_t)j * 128 + i] = f2bf(acc[fm][fn][r]);
            }
}

// ---------------------------------------------------------------------------
// CSR (dst only): scan + scatter
// ---------------------------------------------------------------------------
__global__ __launch_bounds__(1024) void scan1_kernel(
    const int* __restrict__ cntd, int* __restrict__ offd, int* __restrict__ curd, int N)
{
    __shared__ int ls[1024];
    const int t = threadIdx.x;
    const int chunk = (N + 1023) >> 10;
    int base = t * chunk;
    int s = 0;
    for (int i = 0; i < chunk; ++i) {
        int idx = base + i;
        if (idx < N) s += cntd[idx];
    }
    ls[t] = s;
    __syncthreads();
    for (int d = 1; d < 1024; d <<= 1) {
        int v = (t >= d) ? ls[t - d] : 0;
        __syncthreads();
        ls[t] += v;
        __syncthreads();
    }
    int run = t ? ls[t - 1] : 0;
    for (int i = 0; i < chunk; ++i) {
        int idx = base + i;
        if (idx < N) {
            offd[idx] = run;
            curd[idx] = run;
            run += cntd[idx];
        }
    }
    if (t == 1023) offd[N] = run;
}

__global__ void scat_kernel(const int* __restrict__ src, const int* __restrict__ dst,
                            int* __restrict__ curd,
                            int* __restrict__ src_d, int* __restrict__ dst_d, int E)
{
    int e = blockIdx.x * 256 + threadIdx.x;
    if (e >= E) return;
    int s = src[e], d = dst[e];
    int pd = atomicAdd(&curd[d], 1);
    src_d[pd] = s;
    dst_d[pd] = d;
}

// ---------------------------------------------------------------------------
// bf16 MFMA GEMM: C(M,NC) = A(M,K) @ BT(NC,K)^T  [+bias][relu]
// 128 x (NTILE*64) tile, 256 threads (4 waves, 2x2), BK=64, XOR-swizzled LDS.
// ---------------------------------------------------------------------------
template <int NTILE, typename OT, bool BIAS, bool RELU>
__global__ __launch_bounds__(256) void gemm_mfma(
    const ushort* __restrict__ A, const ushort* __restrict__ BT,
    const float* __restrict__ bias,
    OT* __restrict__ C, int M, int K, int NC)
{
    constexpr int FN = NTILE * 2;        // b-frags per wave
    constexpr int WN = NTILE * 32;       // wave n-width
    __shared__ char lds[16384 + NTILE * 8192];
    char* AsB = lds;                     // 128 rows x 128B, XOR swizzled
    char* BsB = lds + 16384;             // NTILE*64 rows x 128B

    const int m0 = blockIdx.y * 128;
    const int n0 = blockIdx.x * (NTILE * 64);
    const int t = threadIdx.x;
    const int lane = t & 63, wid = t >> 6;
    const int wm = wid >> 1, wn = wid & 1;
    const int frow = lane & 15, kgrp = lane >> 4;

    f32x4 acc[4][FN] = {};

    for (int kk = 0; kk < K; kk += 64) {
#pragma unroll
        for (int it = 0; it < 4; ++it) {            // stage A: 128x64 bf16
            int q = it * 256 + t;
            int r = q >> 3, c8 = (q & 7) * 8;
            int gm = m0 + r;
            short8 v = {};
            if (gm < M) v = *reinterpret_cast<const short8*>(&A[(size_t)gm * K + kk + c8]);
            *reinterpret_cast<short8*>(&AsB[r * 128 + ((c8 * 2) ^ ((r & 7) << 4))]) = v;
        }
#pragma unroll
        for (int it = 0; it < 2 * NTILE; ++it) {    // stage B: (NTILE*64)x64 bf16
            int q = it * 256 + t;
            int r = q >> 3, c8 = (q & 7) * 8;
            short8 v = *reinterpret_cast<const short8*>(&BT[(size_t)(n0 + r) * K + kk + c8]);
            *reinterpret_cast<short8*>(&BsB[r * 128 + ((c8 * 2) ^ ((r & 7) << 4))]) = v;
        }
        __syncthreads();
#pragma unroll
        for (int kp = 0; kp < 2; ++kp) {
            const int koffb = kp * 64 + kgrp * 16;
            short8 b[FN];
#pragma unroll
            for (int fn = 0; fn < FN; ++fn) {
                int col = wn * WN + fn * 16 + frow;
                b[fn] = *reinterpret_cast<const short8*>(&BsB[col * 128 + (koffb ^ ((col & 7) << 4))]);
            }
#pragma unroll
            for (int fm = 0; fm < 4; ++fm) {
                int row = wm * 64 + fm * 16 + frow;
                short8 a = *reinterpret_cast<const short8*>(&AsB[row * 128 + (koffb ^ ((row & 7) << 4))]);
#pragma unroll
                for (int fn = 0; fn < FN; ++fn)
                    acc[fm][fn] = __builtin_amdgcn_mfma_f32_16x16x32_bf16(a, b[fn], acc[fm][fn], 0, 0, 0);
            }
        }
        __syncthreads();
    }

#pragma unroll
    for (int fm = 0; fm < 4; ++fm)
#pragma unroll
        for (int fn = 0; fn < FN; ++fn)
#pragma unroll
            for (int r = 0; r < 4; ++r) {
                int gm = m0 + wm * 64 + fm * 16 + kgrp * 4 + r;   // row = (lane>>4)*4+reg
                int gn = n0 + wn * WN + fn * 16 + frow;           // col = lane&15
                if (gm >= M) continue;
                float v = acc[fm][fn][r];
                if (BIAS) v += bias[gn];
                if (RELU) v = fmaxf(v, 0.f);
                stC(&C[(size_t)gm * NC + gn], v);
            }
}

// ---------------------------------------------------------------------------
// f2 GEMM (M x 512 @ 512 x 128) + bias + residual + LayerNorm2, fused.
// 128x128 tile (grid.x == 1), LDS-staged row LN in epilogue.
// ---------------------------------------------------------------------------
__global__ __launch_bounds__(256) void gemm_f2ln_kernel(
    const ushort* __restrict__ A, const ushort* __restrict__ BT,
    const float* __restrict__ bias, const float* __restrict__ res,
    const float* __restrict__ g, const float* __restrict__ bb,
    float* __restrict__ out, int M)
{
    constexpr int K = 512, NC = 128;
    __shared__ char lds[65536];
    char* AsB = lds;            // 128 rows x 128B
    char* BsB = lds + 16384;    // 128 rows x 128B

    const int m0 = blockIdx.y * 128;
    const int t = threadIdx.x;
    const int lane = t & 63, wid = t >> 6;
    const int wm = wid >> 1, wn = wid & 1;
    const int frow = lane & 15, kgrp = lane >> 4;

    f32x4 acc[4][4] = {};

    for (int kk = 0; kk < K; kk += 64) {
#pragma unroll
        for (int it = 0; it < 4; ++it) {
            int q = it * 256 + t;
            int r = q >> 3, c8 = (q & 7) * 8;
            int gm = m0 + r;
            short8 v = {};
            if (gm < M) v = *reinterpret_cast<const short8*>(&A[(size_t)gm * K + kk + c8]);
            *reinterpret_cast<short8*>(&AsB[r * 128 + ((c8 * 2) ^ ((r & 7) << 4))]) = v;
        }
#pragma unroll
        for (int it = 0; it < 4; ++it) {
            int q = it * 256 + t;
            int r = q >> 3, c8 = (q & 7) * 8;
            short8 v = *reinterpret_cast<const short8*>(&BT[(size_t)r * K + kk + c8]);
            *reinterpret_cast<short8*>(&BsB[r * 128 + ((c8 * 2) ^ ((r & 7) << 4))]) = v;
        }
        __syncthreads();
#pragma unroll
        for (int kp = 0; kp < 2; ++kp) {
            const int koffb = kp * 64 + kgrp * 16;
            short8 b[4];
#pragma unroll
            for (int fn = 0; fn < 4; ++fn) {
                int col = wn * 64 + fn * 16 + frow;
                b[fn] = *reinterpret_cast<const short8*>(&BsB[col * 128 + (koffb ^ ((col & 7) << 4))]);
            }
#pragma unroll
            for (int fm = 0; fm < 4; ++fm) {
                int row = wm * 64 + fm * 16 + frow;
                short8 a = *reinterpret_cast<const short8*>(&AsB[row * 128 + (koffb ^ ((row & 7) << 4))]);
#pragma unroll
                for (int fn = 0; fn < 4; ++fn)
                    acc[fm][fn] = __builtin_amdgcn_mfma_f32_16x16x32_bf16(a, b[fn], acc[fm][fn], 0, 0, 0);
            }
        }
        __syncthreads();
    }

    // epilogue: stage (acc + bias) into fp32 LDS [128][128] (xor-swizzled)
    float* Cf = (float*)lds;
#pragma unroll
    for (int fm = 0; fm < 4; ++fm)
#pragma unroll
        for (int fn = 0; fn < 4; ++fn)
#pragma unroll
            for (int r = 0; r < 4; ++r) {
                int row = wm * 64 + fm * 16 + kgrp * 4 + r;
                int col = wn * 64 + fn * 16 + frow;
                Cf[row * 128 + (col ^ (((row >> 2) & 7) << 2))] = acc[fm][fn][r] + bias[col];
            }
    __syncthreads();

    // LN: wave wid handles rows [wid*32, wid*32+32)
    for (int rr = 0; rr < 32; ++rr) {
        int row = wid * 32 + rr;
        int gm = m0 + row;
        if (gm >= M) continue;
        int xorv = ((row >> 2) & 7) << 2;
        float vx = Cf[row * 128 + ((2 * lane) ^ xorv)];
        float vy = Cf[row * 128 + ((2 * lane + 1) ^ xorv)];
        float2 rs = reinterpret_cast<const float2*>(res)[(size_t)gm * 64 + lane];
        vx += rs.x; vy += rs.y;
        float sum = vx + vy;
#pragma unroll
        for (int off = 32; off; off >>= 1) sum += __shfl_xor(sum, off);
        float mean = sum * (1.f / 128.f);
        float cx = vx - mean, cy = vy - mean;
        float vs = cx * cx + cy * cy;
#pragma unroll
        for (int off = 32; off; off >>= 1) vs += __shfl_xor(vs, off);
        float r = rsqrtf(vs * (1.f / 128.f) + 1e-5f);
        float2 gg = reinterpret_cast<const float2*>(g)[lane];
        float2 bbv = reinterpret_cast<const float2*>(bb)[lane];
        float2 o;
        o.x = cx * r * gg.x + bbv.x;
        o.y = cy * r * gg.y + bbv.y;
        reinterpret_cast<float2*>(out)[(size_t)gm * 64 + lane] = o;
    }
}

// ---------------------------------------------------------------------------
// Edge logits: 16 lanes per edge (4 edges/wave), dst-sorted order.
// DPP reduction (VALU) within the 16-lane group. Writes unnormalized exp.
// ---------------------------------------------------------------------------
__global__ __launch_bounds__(256) void edge_logits2_kernel(
    const ushort* __restrict__ featbf, const ushort* __restrict__ GVO,
    const int* __restrict__ src_d, const int* __restrict__ dst_d,
    float* __restrict__ exws, int E)
{
    int w = (int)((blockIdx.x * 256 + threadIdx.x) >> 6);
    int lane = threadIdx.x & 63;
    int el = lane >> 4, li = lane & 15;
    int p = w * 4 + el;
    if (p >= E) return;
    int s = src_d[p], d = dst_d[p];
    uint4 f = reinterpret_cast<const uint4*>(featbf)[(size_t)s * 16 + li];
    const uint4* Grow = reinterpret_cast<const uint4*>(GVO) + (size_t)d * 256 + li;
    float sel = 0.f;
#pragma unroll
    for (int h = 0; h < 8; ++h) {
        uint4 g = Grow[h * 16];
        float pv = bf_lo(g.x) * bf_lo(f.x) + bf_hi(g.x) * bf_hi(f.x);
        pv += bf_lo(g.y) * bf_lo(f.y) + bf_hi(g.y) * bf_hi(f.y);
        pv += bf_lo(g.z) * bf_lo(f.z) + bf_hi(g.z) * bf_hi(f.z);
        pv += bf_lo(g.w) * bf_lo(f.w) + bf_hi(g.w) * bf_hi(f.w);
        pv = DPPADD(pv, 0xB1);   // xor 1
        pv = DPPADD(pv, 0x4E);   // xor 2
        pv = DPPADD(pv, 0x141);  // row_half_mirror
        pv = DPPADD(pv, 0x128);  // row_ror:8
        sel = (li == h) ? pv : sel;
    }
    float u = fminf(fmaxf(sel, -5.f), 5.f);
    float ex = __expf(u);
    if (li < 8) exws[(size_t)p * 8 + li] = ex;
}

// ---------------------------------------------------------------------------
// Fused den + weighted-V aggregation + LayerNorm1. One wave per dst node.
// pass1: den_h (coalesced exws reads); pass2: gather VO[src] per in-edge,
// acc += (ex_h/den_h)*VO; then uh = LN1(feat + acc), uhbf = bf16(uh).
// ---------------------------------------------------------------------------
__global__ __launch_bounds__(256) void aggden_ln1_kernel(
    const ushort* __restrict__ GVO, const int* __restrict__ src_d,
    const int* __restrict__ offd, const float* __restrict__ exws,
    const float* __restrict__ feat, const float* __restrict__ g1,
    const float* __restrict__ b1, float* __restrict__ uh,
    ushort* __restrict__ uhbf, int N)
{
    int d = (int)((blockIdx.x * 256 + threadIdx.x) >> 6);
    int lane = threadIdx.x & 63;
    if (d >= N) return;
    const int lo = offd[d], hi = offd[d + 1];

    // pass1: den per head (lane = es*8 + h)
    int h = lane & 7;
    float den = 0.f;
    for (int i = lo + (lane >> 3); i < hi; i += 8)
        den += exws[(size_t)i * 8 + h];
    den += __shfl_xor(den, 8);
    den += __shfl_xor(den, 16);
    den += __shfl_xor(den, 32);
    float rh = 1.f / den;
    float rv0 = __shfl(rh, 0), rv1 = __shfl(rh, 1), rv2 = __shfl(rh, 2), rv3 = __shfl(rh, 3);
    float rv4 = __shfl(rh, 4), rv5 = __shfl(rh, 5), rv6 = __shfl(rh, 6), rv7 = __shfl(rh, 7);

    // pass2: gather-accumulate
    float acc0 = 0.f, acc1 = 0.f;
    int snext = (lo < hi) ? src_d[lo] : 0;
    for (int i = lo; i < hi; ++i) {
        int s = snext;
        if (i + 1 < hi) snext = src_d[i + 1];
        float4 e0 = *reinterpret_cast<const float4*>(&exws[(size_t)i * 8]);
        float4 e1 = *reinterpret_cast<const float4*>(&exws[(size_t)i * 8 + 4]);
        const uint* vrow = reinterpret_cast<const uint*>(GVO + (size_t)s * 2048 + 1024);
        uint gv0 = vrow[0 * 64 + lane], gv1 = vrow[1 * 64 + lane];
        uint gv2 = vrow[2 * 64 + lane], gv3 = vrow[3 * 64 + lane];
        uint gv4 = vrow[4 * 64 + lane], gv5 = vrow[5 * 64 + lane];
        uint gv6 = vrow[6 * 64 + lane], gv7 = vrow[7 * 64 + lane];
        float a0 = e0.x * rv0, a1 = e0.y * rv1, a2 = e0.z * rv2, a3 = e0.w * rv3;
        float a4 = e1.x * rv4, a5 = e1.y * rv5, a6 = e1.z * rv6, a7 = e1.w * rv7;
        acc0 += a0 * bf_lo(gv0) + a1 * bf_lo(gv1) + a2 * bf_lo(gv2) + a3 * bf_lo(gv3)
              + a4 * bf_lo(gv4) + a5 * bf_lo(gv5) + a6 * bf_lo(gv6) + a7 * bf_lo(gv7);
        acc1 += a0 * bf_hi(gv0) + a1 * bf_hi(gv1) + a2 * bf_hi(gv2) + a3 * bf_hi(gv3)
              + a4 * bf_hi(gv4) + a5 * bf_hi(gv5) + a6 * bf_hi(gv6) + a7 * bf_hi(gv7);
    }

    float2 v = reinterpret_cast<const float2*>(feat)[(size_t)d * 64 + lane];
    v.x += acc0;
    v.y += acc1;
    float sum = v.x + v.y;
#pragma unroll
    for (int off = 32; off; off >>= 1) sum += __shfl_xor(sum, off);
    float mean = sum * (1.f / 128.f);
    float cx = v.x - mean, cy = v.y - mean;
    float vs = cx * cx + cy * cy;
#pragma unroll
    for (int off = 32; off; off >>= 1) vs += __shfl_xor(vs, off);
    float r = rsqrtf(vs * (1.f / 128.f) + 1e-5f);
    float2 gg = reinterpret_cast<const float2*>(g1)[lane];
    float2 bb = reinterpret_cast<const float2*>(b1)[lane];
    float2 o;
    o.x = cx * r * gg.x + bb.x;
    o.y = cy * r * gg.y + bb.y;
    reinterpret_cast<float2*>(uh)[(size_t)d * 64 + lane] = o;
    ushort2 ob; ob.x = f2bf(o.x); ob.y = f2bf(o.y);
    reinterpret_cast<ushort2*>(uhbf)[(size_t)d * 64 + lane] = ob;
}

// ---------------------------------------------------------------------------
extern "C" void kernel_launch(void* const* d_in, const int* in_sizes, int n_in,
                              void* d_out, int out_size, void* d_ws, size_t ws_size,
                              hipStream_t stream)
{
    const float* feat = (const float*)d_in[0];
    const int*   src  = (const int*)d_in[1];
    const int*   dst  = (const int*)d_in[2];
    const float* Wq   = (const float*)d_in[3];
    const float* Wk   = (const float*)d_in[4];
    const float* Wv   = (const float*)d_in[5];
    const float* Wo   = (const float*)d_in[6];
    const float* g1   = (const float*)d_in[7];
    const float* b1   = (const float*)d_in[8];
    const float* W1   = (const float*)d_in[9];
    const float* bf1  = (const float*)d_in[10];
    const float* W2   = (const float*)d_in[11];
    const float* bf2  = (const float*)d_in[12];
    const float* g2   = (const float*)d_in[13];
    const float* b2   = (const float*)d_in[14];
    const int N = in_sizes[0] / 128;
    const int E = in_sizes[1];
    float* out = (float*)d_out;

    char* w = (char*)d_ws;
    auto alloc = [&](size_t bytes) {
        char* p = w;
        w += (bytes + 255) & ~(size_t)255;
        return p;
    };
    ushort* MPT    = (ushort*)alloc((size_t)2048 * 128 * 2);
    float*  WoT    = (float*)alloc((size_t)128 * 1024 * 4);
    ushort* W1T    = (ushort*)alloc((size_t)512 * 128 * 2);
    ushort* W2T    = (ushort*)alloc((size_t)128 * 512 * 2);
    ushort* featbf = (ushort*)alloc((size_t)N * 128 * 2);
    ushort* GVO    = (ushort*)alloc((size_t)N * 2048 * 2);
    float*  exws   = (float*)alloc((size_t)E * 8 * 4);
    int*    cntd   = (int*)alloc((size_t)N * 4);
    int*    offd   = (int*)alloc((size_t)(N + 1) * 4);
    int*    curd   = (int*)alloc((size_t)N * 4);
    int*    src_d  = (int*)alloc((size_t)E * 4);
    int*    dst_d  = (int*)alloc((size_t)E * 4);
    float*  uh     = (float*)alloc((size_t)N * 128 * 4);
    ushort* uhbf   = (ushort*)alloc((size_t)N * 128 * 2);
    ushort* f1     = (ushort*)alloc((size_t)N * 512 * 2);

    hipMemsetAsync(cntd, 0, (size_t)N * 4, stream);

    // --- fused prep: f2bf + 3 transposes + dst histogram ---
    int nf = (N * 32 + 255) / 256;
    int eb = (E + 255) / 256;
    prep0_kernel<<<nf + 64 + eb, 256, 0, stream>>>(
        feat, featbf, Wo, WoT, W1, W1T, W2, W2T, dst, cntd, N, E);

    // --- CSR scan + scatter, MPT build ---
    scan1_kernel<<<1, 1024, 0, stream>>>(cntd, offd, curd, N);
    scat_kernel<<<eb, 256, 0, stream>>>(src, dst, curd, src_d, dst_d, E);
    mpt_mfma_kernel<<<16, 256, 0, stream>>>(Wq, Wk, Wv, WoT, MPT);

    // --- GVO = feat @ [M | P]  (N x 2048, bf16 out), 128x128 tile ---
    dim3 gv_grid(2048 / 128, (N + 127) / 128);
    gemm_mfma<2, ushort, false, false><<<gv_grid, 256, 0, stream>>>(
        featbf, MPT, nullptr, GVO, N, 128, 2048);

    // --- edge phase ---
    edge_logits2_kernel<<<(E + 15) / 16, 256, 0, stream>>>(featbf, GVO, src_d, dst_d, exws, E);
    int nwaves_n = (N * 64 + 255) / 256;
    aggden_ln1_kernel<<<nwaves_n, 256, 0, stream>>>(
        GVO, src_d, offd, exws, feat, g1, b1, uh, uhbf, N);

    // --- FFN ---
    dim3 f1_grid(512 / 128, (N + 127) / 128);
    gemm_mfma<2, ushort, true, true><<<f1_grid, 256, 0, stream>>>(
        uhbf, W1T, bf1, f1, N, 128, 512);
    dim3 f2_grid(1, (N + 127) / 128);
    gemm_f2ln_kernel<<<f2_grid, 256, 0, stream>>>(
        f1, W2T, bf2, uh, g2, b2, out, N);
}

// Round 8
// 139.852 us; speedup vs baseline: 1.5479x; 1.1006x over previous
//
#include <hip/hip_runtime.h>

typedef unsigned int uint;
typedef unsigned short ushort;
typedef __attribute__((ext_vector_type(8))) short short8;
typedef __attribute__((ext_vector_type(4))) float f32x4;

#define DEV static __device__ __forceinline__

DEV float bf_lo(uint v) { return __uint_as_float(v << 16); }
DEV float bf_hi(uint v) { return __uint_as_float(v & 0xffff0000u); }
DEV ushort f2bf(float f) {
    uint u = __float_as_uint(f);
    u += 0x7fffu + ((u >> 16) & 1u);   // round-to-nearest-even
    return (ushort)(u >> 16);
}
DEV void stC(float* p, float v) { *p = v; }
DEV void stC(ushort* p, float v) { *p = f2bf(v); }

// VALU-speed cross-lane add via DPP (ctrl must be a literal)
#define DPPADD(v, ctrl) \
    ((v) + __int_as_float(__builtin_amdgcn_mov_dpp(__float_as_int(v), (ctrl), 0xF, 0xF, true)))

// ---------------------------------------------------------------------------
// zero int buffer (int4 granules) — replaces 41us rocclr fill
// ---------------------------------------------------------------------------
__global__ __launch_bounds__(256) void zero_kernel(int4* __restrict__ p, int n4)
{
    int i = blockIdx.x * 256 + threadIdx.x;
    if (i < n4) p[i] = int4{0, 0, 0, 0};
}

// ---------------------------------------------------------------------------
// 64x64 tiled transpose body (in fp32 [R][C] -> out [C][R] fp32/bf16)
// ---------------------------------------------------------------------------
template <typename OT>
DEV void transp_body(float (*tile)[65], const float* __restrict__ in,
                     OT* __restrict__ out, int R, int C, int bid, int t)
{
    const int nbx = C >> 6;
    const int bx = bid % nbx, by = bid / nbx;
#pragma unroll
    for (int it = 0; it < 4; ++it) {
        int idx = it * 256 + t;
        int rr = idx >> 4, cc4 = (idx & 15) * 4;
        float4 v = *reinterpret_cast<const float4*>(in + (size_t)(by * 64 + rr) * C + bx * 64 + cc4);
        tile[cc4][rr] = v.x; tile[cc4 + 1][rr] = v.y;
        tile[cc4 + 2][rr] = v.z; tile[cc4 + 3][rr] = v.w;
    }
    __syncthreads();
#pragma unroll
    for (int it = 0; it < 4; ++it) {
        int idx = it * 256 + t;
        int cc = idx >> 4, rr4 = (idx & 15) * 4;
        OT* po = out + (size_t)(bx * 64 + cc) * R + by * 64 + rr4;
        if constexpr (__is_same(OT, float)) {
            float4 o = { tile[cc][rr4], tile[cc][rr4 + 1], tile[cc][rr4 + 2], tile[cc][rr4 + 3] };
            *reinterpret_cast<float4*>(po) = o;
        } else {
            ushort4 o = { f2bf(tile[cc][rr4]), f2bf(tile[cc][rr4 + 1]),
                          f2bf(tile[cc][rr4 + 2]), f2bf(tile[cc][rr4 + 3]) };
            *reinterpret_cast<ushort4*>(po) = o;
        }
    }
}

// ---------------------------------------------------------------------------
// Fused prep: [f2bf feat] [transp Wo fp32] [transp W1 bf16] [transp W2 bf16]
//             [CSR dst-histogram]   via blockIdx-range dispatch
// ---------------------------------------------------------------------------
__global__ __launch_bounds__(256) void prep0_kernel(
    const float* __restrict__ feat, ushort* __restrict__ featbf,
    const float* __restrict__ Wo, float* __restrict__ WoT,
    const float* __restrict__ W1, ushort* __restrict__ W1T,
    const float* __restrict__ W2, ushort* __restrict__ W2T,
    const int* __restrict__ dst, int* __restrict__ cntd, int N, int E)
{
    __shared__ float tile[64][65];
    const int nf = (N * 32 + 255) / 256;
    const int b = blockIdx.x, t = threadIdx.x;
    if (b < nf) {
        int i = b * 256 + t;
        if (i >= N * 32) return;
        float4 v = reinterpret_cast<const float4*>(feat)[i];
        ushort4 o;
        o.x = f2bf(v.x); o.y = f2bf(v.y); o.z = f2bf(v.z); o.w = f2bf(v.w);
        reinterpret_cast<ushort4*>(featbf)[i] = o;
    } else if (b < nf + 32) {
        transp_body<float>(tile, Wo, WoT, 1024, 128, b - nf, t);
    } else if (b < nf + 48) {
        transp_body<ushort>(tile, W1, W1T, 128, 512, b - nf - 32, t);
    } else if (b < nf + 64) {
        transp_body<ushort>(tile, W2, W2T, 512, 128, b - nf - 48, t);
    } else {
        int e = (b - nf - 64) * 256 + t;
        if (e >= E) return;
        atomicAdd(&cntd[dst[e]], 1);
    }
}

// ---------------------------------------------------------------------------
// MPT build via MFMA. 16 workgroups: part = blockIdx>>3, h = blockIdx&7.
// ---------------------------------------------------------------------------
__global__ __launch_bounds__(256) void mpt_mfma_kernel(
    const float* __restrict__ Wq, const float* __restrict__ Wk,
    const float* __restrict__ Wv, const float* __restrict__ WoT,
    ushort* __restrict__ MPT)
{
    __shared__ char lds[65536];
    char* As = lds;            // 128 rows(j) x 256B (128 bf16), XOR swizzled
    char* Bs = lds + 32768;    // 128 rows(i) x 256B

    const int part = blockIdx.x >> 3, h = blockIdx.x & 7;
    const int t = threadIdx.x;
    const int lane = t & 63, w = t >> 6;
    const int frow = lane & 15, kgrp = lane >> 4;

    const float* Asrc = part ? WoT : Wk;
    const float* Bsrc = part ? Wv : Wq;
    const float ascale = part ? 1.f : 0.08838834764831845f;

#pragma unroll
    for (int it = 0; it < 16; ++it) {
        int idx = it * 256 + t;
        int r = idx >> 5, c4 = (idx & 31) * 4;
        size_t goff = (size_t)r * 1024 + h * 128 + c4;
        float4 va = *reinterpret_cast<const float4*>(Asrc + goff);
        ushort4 ua = { f2bf(va.x * ascale), f2bf(va.y * ascale),
                       f2bf(va.z * ascale), f2bf(va.w * ascale) };
        *reinterpret_cast<ushort4*>(&As[r * 256 + ((c4 * 2) ^ ((r & 7) << 4))]) = ua;
        float4 vb = *reinterpret_cast<const float4*>(Bsrc + goff);
        ushort4 ub = { f2bf(vb.x), f2bf(vb.y), f2bf(vb.z), f2bf(vb.w) };
        *reinterpret_cast<ushort4*>(&Bs[r * 256 + ((c4 * 2) ^ ((r & 7) << 4))]) = ub;
    }
    __syncthreads();

    f32x4 acc[2][8] = {};
#pragma unroll
    for (int ks = 0; ks < 4; ++ks) {
        int koff = ks * 64 + kgrp * 16;
        short8 b[8];
#pragma unroll
        for (int fn = 0; fn < 8; ++fn) {
            int col = fn * 16 + frow;
            b[fn] = *reinterpret_cast<const short8*>(&Bs[col * 256 + (koff ^ ((col & 7) << 4))]);
        }
#pragma unroll
        for (int fm = 0; fm < 2; ++fm) {
            int row = w * 32 + fm * 16 + frow;
            short8 a = *reinterpret_cast<const short8*>(&As[row * 256 + (koff ^ ((row & 7) << 4))]);
#pragma unroll
            for (int fn = 0; fn < 8; ++fn)
                acc[fm][fn] = __builtin_amdgcn_mfma_f32_16x16x32_bf16(a, b[fn], acc[fm][fn], 0, 0, 0);
        }
    }

    const size_t base = ((size_t)part * 1024 + h * 128) * 128;
#pragma unroll
    for (int fm = 0; fm < 2; ++fm)
#pragma unroll
        for (int fn = 0; fn < 8; ++fn)
#pragma unroll
            for (int r = 0; r < 4; ++r) {
                int j = w * 32 + fm * 16 + kgrp * 4 + r;
                int i = fn * 16 + frow;
                MPT[base + (size_t)j * 128 + i] = f2bf(acc[fm][fn][r]);
            }
}

// ---------------------------------------------------------------------------
// CSR (dst only): scan + scatter
// ---------------------------------------------------------------------------
__global__ __launch_bounds__(1024) void scan1_kernel(
    const int* __restrict__ cntd, int* __restrict__ offd, int* __restrict__ curd, int N)
{
    __shared__ int ls[1024];
    const int t = threadIdx.x;
    const int chunk = (N + 1023) >> 10;
    int base = t * chunk;
    int s = 0;
    for (int i = 0; i < chunk; ++i) {
        int idx = base + i;
        if (idx < N) s += cntd[idx];
    }
    ls[t] = s;
    __syncthreads();
    for (int d = 1; d < 1024; d <<= 1) {
        int v = (t >= d) ? ls[t - d] : 0;
        __syncthreads();
        ls[t] += v;
        __syncthreads();
    }
    int run = t ? ls[t - 1] : 0;
    for (int i = 0; i < chunk; ++i) {
        int idx = base + i;
        if (idx < N) {
            offd[idx] = run;
            curd[idx] = run;
            run += cntd[idx];
        }
    }
    if (t == 1023) offd[N] = run;
}

__global__ void scat_kernel(const int* __restrict__ src, const int* __restrict__ dst,
                            int* __restrict__ curd,
                            int* __restrict__ src_d, int* __restrict__ dst_d, int E)
{
    int e = blockIdx.x * 256 + threadIdx.x;
    if (e >= E) return;
    int s = src[e], d = dst[e];
    int pd = atomicAdd(&curd[d], 1);
    src_d[pd] = s;
    dst_d[pd] = d;
}

// ---------------------------------------------------------------------------
// bf16 MFMA GEMM: C(M,NC) = A(M,K) @ BT(NC,K)^T  [+bias][relu][+res]
// 128 x (NTILE*64) tile, 256 threads (4 waves, 2x2), BK=64, XOR-swizzled LDS.
// ---------------------------------------------------------------------------
template <int NTILE, typename OT, bool BIAS, bool RELU, bool RES>
__global__ __launch_bounds__(256) void gemm_mfma(
    const ushort* __restrict__ A, const ushort* __restrict__ BT,
    const float* __restrict__ bias, const float* __restrict__ res,
    OT* __restrict__ C, int M, int K, int NC)
{
    constexpr int FN = NTILE * 2;        // b-frags per wave
    constexpr int WN = NTILE * 32;       // wave n-width
    __shared__ char lds[16384 + NTILE * 8192];
    char* AsB = lds;                     // 128 rows x 128B, XOR swizzled
    char* BsB = lds + 16384;             // NTILE*64 rows x 128B

    const int m0 = blockIdx.y * 128;
    const int n0 = blockIdx.x * (NTILE * 64);
    const int t = threadIdx.x;
    const int lane = t & 63, wid = t >> 6;
    const int wm = wid >> 1, wn = wid & 1;
    const int frow = lane & 15, kgrp = lane >> 4;

    f32x4 acc[4][FN] = {};

    for (int kk = 0; kk < K; kk += 64) {
#pragma unroll
        for (int it = 0; it < 4; ++it) {            // stage A: 128x64 bf16
            int q = it * 256 + t;
            int r = q >> 3, c8 = (q & 7) * 8;
            int gm = m0 + r;
            short8 v = {};
            if (gm < M) v = *reinterpret_cast<const short8*>(&A[(size_t)gm * K + kk + c8]);
            *reinterpret_cast<short8*>(&AsB[r * 128 + ((c8 * 2) ^ ((r & 7) << 4))]) = v;
        }
#pragma unroll
        for (int it = 0; it < 2 * NTILE; ++it) {    // stage B: (NTILE*64)x64 bf16
            int q = it * 256 + t;
            int r = q >> 3, c8 = (q & 7) * 8;
            short8 v = *reinterpret_cast<const short8*>(&BT[(size_t)(n0 + r) * K + kk + c8]);
            *reinterpret_cast<short8*>(&BsB[r * 128 + ((c8 * 2) ^ ((r & 7) << 4))]) = v;
        }
        __syncthreads();
#pragma unroll
        for (int kp = 0; kp < 2; ++kp) {
            const int koffb = kp * 64 + kgrp * 16;
            short8 b[FN];
#pragma unroll
            for (int fn = 0; fn < FN; ++fn) {
                int col = wn * WN + fn * 16 + frow;
                b[fn] = *reinterpret_cast<const short8*>(&BsB[col * 128 + (koffb ^ ((col & 7) << 4))]);
            }
#pragma unroll
            for (int fm = 0; fm < 4; ++fm) {
                int row = wm * 64 + fm * 16 + frow;
                short8 a = *reinterpret_cast<const short8*>(&AsB[row * 128 + (koffb ^ ((row & 7) << 4))]);
#pragma unroll
                for (int fn = 0; fn < FN; ++fn)
                    acc[fm][fn] = __builtin_amdgcn_mfma_f32_16x16x32_bf16(a, b[fn], acc[fm][fn], 0, 0, 0);
            }
        }
        __syncthreads();
    }

#pragma unroll
    for (int fm = 0; fm < 4; ++fm)
#pragma unroll
        for (int fn = 0; fn < FN; ++fn)
#pragma unroll
            for (int r = 0; r < 4; ++r) {
                int gm = m0 + wm * 64 + fm * 16 + kgrp * 4 + r;   // row = (lane>>4)*4+reg
                int gn = n0 + wn * WN + fn * 16 + frow;           // col = lane&15
                if (gm >= M) continue;
                float v = acc[fm][fn][r];
                if (BIAS) v += bias[gn];
                if (RELU) v = fmaxf(v, 0.f);
                if (RES) v += res[(size_t)gm * NC + gn];
                stC(&C[(size_t)gm * NC + gn], v);
            }
}

// ---------------------------------------------------------------------------
// Edge logits: 16 lanes per edge (4 edges/wave), dst-sorted order.
// ---------------------------------------------------------------------------
__global__ __launch_bounds__(256) void edge_logits2_kernel(
    const ushort* __restrict__ featbf, const ushort* __restrict__ GVO,
    const int* __restrict__ src_d, const int* __restrict__ dst_d,
    float* __restrict__ exws, int E)
{
    int w = (int)((blockIdx.x * 256 + threadIdx.x) >> 6);
    int lane = threadIdx.x & 63;
    int el = lane >> 4, li = lane & 15;
    int p = w * 4 + el;
    if (p >= E) return;
    int s = src_d[p], d = dst_d[p];
    uint4 f = reinterpret_cast<const uint4*>(featbf)[(size_t)s * 16 + li];
    const uint4* Grow = reinterpret_cast<const uint4*>(GVO) + (size_t)d * 256 + li;
    float sel = 0.f;
#pragma unroll
    for (int h = 0; h < 8; ++h) {
        uint4 g = Grow[h * 16];
        float pv = bf_lo(g.x) * bf_lo(f.x) + bf_hi(g.x) * bf_hi(f.x);
        pv += bf_lo(g.y) * bf_lo(f.y) + bf_hi(g.y) * bf_hi(f.y);
        pv += bf_lo(g.z) * bf_lo(f.z) + bf_hi(g.z) * bf_hi(f.z);
        pv += bf_lo(g.w) * bf_lo(f.w) + bf_hi(g.w) * bf_hi(f.w);
        pv = DPPADD(pv, 0xB1);   // xor 1
        pv = DPPADD(pv, 0x4E);   // xor 2
        pv = DPPADD(pv, 0x141);  // row_half_mirror
        pv = DPPADD(pv, 0x128);  // row_ror:8
        sel = (li == h) ? pv : sel;
    }
    float u = fminf(fmaxf(sel, -5.f), 5.f);
    float ex = __expf(u);
    if (li < 8) exws[(size_t)p * 8 + li] = ex;
}

// ---------------------------------------------------------------------------
// Fused den + weighted-V aggregation + LayerNorm1. One wave per dst node.
// ---------------------------------------------------------------------------
__global__ __launch_bounds__(256) void aggden_ln1_kernel(
    const ushort* __restrict__ GVO, const int* __restrict__ src_d,
    const int* __restrict__ offd, const float* __restrict__ exws,
    const float* __restrict__ feat, const float* __restrict__ g1,
    const float* __restrict__ b1, float* __restrict__ uh,
    ushort* __restrict__ uhbf, int N)
{
    int d = (int)((blockIdx.x * 256 + threadIdx.x) >> 6);
    int lane = threadIdx.x & 63;
    if (d >= N) return;
    const int lo = offd[d], hi = offd[d + 1];

    // pass1: den per head (lane = es*8 + h)
    int h = lane & 7;
    float den = 0.f;
    for (int i = lo + (lane >> 3); i < hi; i += 8)
        den += exws[(size_t)i * 8 + h];
    den += __shfl_xor(den, 8);
    den += __shfl_xor(den, 16);
    den += __shfl_xor(den, 32);
    float rh = 1.f / den;
    float rv0 = __shfl(rh, 0), rv1 = __shfl(rh, 1), rv2 = __shfl(rh, 2), rv3 = __shfl(rh, 3);
    float rv4 = __shfl(rh, 4), rv5 = __shfl(rh, 5), rv6 = __shfl(rh, 6), rv7 = __shfl(rh, 7);

    // pass2: gather-accumulate
    float acc0 = 0.f, acc1 = 0.f;
    int snext = (lo < hi) ? src_d[lo] : 0;
    for (int i = lo; i < hi; ++i) {
        int s = snext;
        if (i + 1 < hi) snext = src_d[i + 1];
        float4 e0 = *reinterpret_cast<const float4*>(&exws[(size_t)i * 8]);
        float4 e1 = *reinterpret_cast<const float4*>(&exws[(size_t)i * 8 + 4]);
        const uint* vrow = reinterpret_cast<const uint*>(GVO + (size_t)s * 2048 + 1024);
        uint gv0 = vrow[0 * 64 + lane], gv1 = vrow[1 * 64 + lane];
        uint gv2 = vrow[2 * 64 + lane], gv3 = vrow[3 * 64 + lane];
        uint gv4 = vrow[4 * 64 + lane], gv5 = vrow[5 * 64 + lane];
        uint gv6 = vrow[6 * 64 + lane], gv7 = vrow[7 * 64 + lane];
        float a0 = e0.x * rv0, a1 = e0.y * rv1, a2 = e0.z * rv2, a3 = e0.w * rv3;
        float a4 = e1.x * rv4, a5 = e1.y * rv5, a6 = e1.z * rv6, a7 = e1.w * rv7;
        acc0 += a0 * bf_lo(gv0) + a1 * bf_lo(gv1) + a2 * bf_lo(gv2) + a3 * bf_lo(gv3)
              + a4 * bf_lo(gv4) + a5 * bf_lo(gv5) + a6 * bf_lo(gv6) + a7 * bf_lo(gv7);
        acc1 += a0 * bf_hi(gv0) + a1 * bf_hi(gv1) + a2 * bf_hi(gv2) + a3 * bf_hi(gv3)
              + a4 * bf_hi(gv4) + a5 * bf_hi(gv5) + a6 * bf_hi(gv6) + a7 * bf_hi(gv7);
    }

    float2 v = reinterpret_cast<const float2*>(feat)[(size_t)d * 64 + lane];
    v.x += acc0;
    v.y += acc1;
    float sum = v.x + v.y;
#pragma unroll
    for (int off = 32; off; off >>= 1) sum += __shfl_xor(sum, off);
    float mean = sum * (1.f / 128.f);
    float cx = v.x - mean, cy = v.y - mean;
    float vs = cx * cx + cy * cy;
#pragma unroll
    for (int off = 32; off; off >>= 1) vs += __shfl_xor(vs, off);
    float r = rsqrtf(vs * (1.f / 128.f) + 1e-5f);
    float2 gg = reinterpret_cast<const float2*>(g1)[lane];
    float2 bb = reinterpret_cast<const float2*>(b1)[lane];
    float2 o;
    o.x = cx * r * gg.x + bb.x;
    o.y = cy * r * gg.y + bb.y;
    reinterpret_cast<float2*>(uh)[(size_t)d * 64 + lane] = o;
    ushort2 ob; ob.x = f2bf(o.x); ob.y = f2bf(o.y);
    reinterpret_cast<ushort2*>(uhbf)[(size_t)d * 64 + lane] = ob;
}

// ---------------------------------------------------------------------------
// Final LayerNorm
// ---------------------------------------------------------------------------
__global__ __launch_bounds__(256) void ln_kernel(
    const float* __restrict__ x, const float* __restrict__ g,
    const float* __restrict__ b, float* __restrict__ out, int M)
{
    int row = (int)((blockIdx.x * 256 + threadIdx.x) >> 6);
    int lane = threadIdx.x & 63;
    if (row >= M) return;
    float2 v = reinterpret_cast<const float2*>(x)[(size_t)row * 64 + lane];
    float sum = v.x + v.y;
#pragma unroll
    for (int off = 32; off; off >>= 1) sum += __shfl_xor(sum, off);
    float mean = sum * (1.f / 128.f);
    float cx = v.x - mean, cy = v.y - mean;
    float vs = cx * cx + cy * cy;
#pragma unroll
    for (int off = 32; off; off >>= 1) vs += __shfl_xor(vs, off);
    float r = rsqrtf(vs * (1.f / 128.f) + 1e-5f);
    float2 gg = reinterpret_cast<const float2*>(g)[lane];
    float2 bb = reinterpret_cast<const float2*>(b)[lane];
    float2 o;
    o.x = cx * r * gg.x + bb.x;
    o.y = cy * r * gg.y + bb.y;
    reinterpret_cast<float2*>(out)[(size_t)row * 64 + lane] = o;
}

// ---------------------------------------------------------------------------
extern "C" void kernel_launch(void* const* d_in, const int* in_sizes, int n_in,
                              void* d_out, int out_size, void* d_ws, size_t ws_size,
                              hipStream_t stream)
{
    const float* feat = (const float*)d_in[0];
    const int*   src  = (const int*)d_in[1];
    const int*   dst  = (const int*)d_in[2];
    const float* Wq   = (const float*)d_in[3];
    const float* Wk   = (const float*)d_in[4];
    const float* Wv   = (const float*)d_in[5];
    const float* Wo   = (const float*)d_in[6];
    const float* g1   = (const float*)d_in[7];
    const float* b1   = (const float*)d_in[8];
    const float* W1   = (const float*)d_in[9];
    const float* bf1  = (const float*)d_in[10];
    const float* W2   = (const float*)d_in[11];
    const float* bf2  = (const float*)d_in[12];
    const float* g2   = (const float*)d_in[13];
    const float* b2   = (const float*)d_in[14];
    const int N = in_sizes[0] / 128;
    const int E = in_sizes[1];
    float* out = (float*)d_out;

    char* w = (char*)d_ws;
    auto alloc = [&](size_t bytes) {
        char* p = w;
        w += (bytes + 255) & ~(size_t)255;
        return p;
    };
    ushort* MPT    = (ushort*)alloc((size_t)2048 * 128 * 2);
    float*  WoT    = (float*)alloc((size_t)128 * 1024 * 4);
    ushort* W1T    = (ushort*)alloc((size_t)512 * 128 * 2);
    ushort* W2T    = (ushort*)alloc((size_t)128 * 512 * 2);
    ushort* featbf = (ushort*)alloc((size_t)N * 128 * 2);
    ushort* GVO    = (ushort*)alloc((size_t)N * 2048 * 2);
    float*  exws   = (float*)alloc((size_t)E * 8 * 4);
    int*    cntd   = (int*)alloc((size_t)((N + 3) & ~3) * 4);
    int*    offd   = (int*)alloc((size_t)(N + 1) * 4);
    int*    curd   = (int*)alloc((size_t)N * 4);
    int*    src_d  = (int*)alloc((size_t)E * 4);
    int*    dst_d  = (int*)alloc((size_t)E * 4);
    float*  uh     = (float*)alloc((size_t)N * 128 * 4);
    ushort* uhbf   = (ushort*)alloc((size_t)N * 128 * 2);
    ushort* f1     = (ushort*)alloc((size_t)N * 512 * 2);
    float*  pre2   = (float*)alloc((size_t)N * 128 * 4);

    // --- zero cntd (custom kernel: rocclr fill costs ~41us in-graph) ---
    int n4 = (N + 3) / 4;
    zero_kernel<<<(n4 + 255) / 256, 256, 0, stream>>>((int4*)cntd, n4);

    // --- fused prep: f2bf + 3 transposes + dst histogram ---
    int nf = (N * 32 + 255) / 256;
    int eb = (E + 255) / 256;
    prep0_kernel<<<nf + 64 + eb, 256, 0, stream>>>(
        feat, featbf, Wo, WoT, W1, W1T, W2, W2T, dst, cntd, N, E);

    // --- CSR scan + scatter, MPT build ---
    scan1_kernel<<<1, 1024, 0, stream>>>(cntd, offd, curd, N);
    scat_kernel<<<eb, 256, 0, stream>>>(src, dst, curd, src_d, dst_d, E);
    mpt_mfma_kernel<<<16, 256, 0, stream>>>(Wq, Wk, Wv, WoT, MPT);

    // --- GVO = feat @ [M | P]  (N x 2048, bf16 out), 128x128 tile ---
    dim3 gv_grid(2048 / 128, (N + 127) / 128);
    gemm_mfma<2, ushort, false, false, false><<<gv_grid, 256, 0, stream>>>(
        featbf, MPT, nullptr, nullptr, GVO, N, 128, 2048);

    // --- edge phase ---
    edge_logits2_kernel<<<(E + 15) / 16, 256, 0, stream>>>(featbf, GVO, src_d, dst_d, exws, E);
    int nwaves_n = (N * 64 + 255) / 256;
    aggden_ln1_kernel<<<nwaves_n, 256, 0, stream>>>(
        GVO, src_d, offd, exws, feat, g1, b1, uh, uhbf, N);

    // --- FFN ---
    dim3 f1_grid(512 / 128, (N + 127) / 128);
    gemm_mfma<2, ushort, true, true, false><<<f1_grid, 256, 0, stream>>>(
        uhbf, W1T, bf1, nullptr, f1, N, 128, 512);
    dim3 f2_grid(128 / 64, (N + 127) / 128);
    gemm_mfma<1, float, true, false, true><<<f2_grid, 256, 0, stream>>>(
        f1, W2T, bf2, uh, pre2, N, 512, 128);

    ln_kernel<<<nwaves_n, 256, 0, stream>>>(pre2, g2, b2, out, N);
}